// Round 9
// baseline (2356.096 us; speedup 1.0000x reference)
//
#include <hip/hip_runtime.h>
#include <hip/hip_bf16.h>

// ---------------------------------------------------------------------------
// LSTM LM forward on MI355X — round 9.
// 3-role persistent recurrence (96 blocks x 256 thr): L0 (h0 self-chain),
// L1a (W1·h0 partials, slack worker), L1b (h1 self-chain). Direct coherent
// fragment loads (no LDS staging), wave-private gate transpose (no block
// barriers on the critical path), amortized cross-chain polls, per-block
// flag stores. All in-loop MFMAs are K=512, 128 weight-VGPRs per wave.
// ---------------------------------------------------------------------------

#define NVOC 32000
#define DIM  512
#define HID  512
#define SEQ  128
#define BAT  32

typedef short s8v __attribute__((ext_vector_type(8)));
typedef short s4v __attribute__((ext_vector_type(4)));
typedef float f4v __attribute__((ext_vector_type(4)));
typedef unsigned long long u64;

__device__ __forceinline__ short f2bf(float f) {
    unsigned u = __builtin_bit_cast(unsigned, f);
    unsigned r = (u + 0x7fffu + ((u >> 16) & 1u)) >> 16;
    return (short)r;
}
__device__ __forceinline__ float bf2f(short s) {
    unsigned u = ((unsigned)(unsigned short)s) << 16;
    return __builtin_bit_cast(float, u);
}
__device__ __forceinline__ float sigm(float x) { return 1.f / (1.f + __expf(-x)); }

__device__ __forceinline__ f4v mf16(s8v a, s8v b, f4v c) {
    return __builtin_amdgcn_mfma_f32_16x16x32_bf16(a, b, c, 0, 0, 0);
}

// coherent (cross-XCD) ops bypassing L1/L2
__device__ __forceinline__ u64 cohload8(const void* p) {
    return __hip_atomic_load((const u64*)p, __ATOMIC_RELAXED,
                             __HIP_MEMORY_SCOPE_AGENT);
}
__device__ __forceinline__ void cohstore4(void* p, unsigned v) {
    __hip_atomic_store((unsigned*)p, v, __ATOMIC_RELAXED,
                       __HIP_MEMORY_SCOPE_AGENT);
}
__device__ __forceinline__ void cohstore8(void* p, u64 v) {
    __hip_atomic_store((u64*)p, v, __ATOMIC_RELAXED,
                       __HIP_MEMORY_SCOPE_AGENT);
}

// 32-flag poll: lanes<32 check flag[l], lanes>=32 duplicate; all 64 must pass
__device__ __forceinline__ void poll32(const unsigned* f, int l, unsigned tgt) {
    const unsigned* p = f + (l & 31);
    while (true) {
        unsigned v = __hip_atomic_load(p, __ATOMIC_RELAXED,
                                       __HIP_MEMORY_SCOPE_AGENT);
        if (__all((int)(v >= tgt))) break;
    }
}
__device__ __forceinline__ void poll32s(const unsigned* f, int l, unsigned tgt) {
    const unsigned* p = f + (l & 31);
    while (true) {
        unsigned v = __hip_atomic_load(p, __ATOMIC_RELAXED,
                                       __HIP_MEMORY_SCOPE_AGENT);
        if (__all((int)(v >= tgt))) break;
        __builtin_amdgcn_s_sleep(1);
    }
}

// K=512 hi/lo MFMA against a [32][512] bf16 coherent buffer.
__device__ __forceinline__ void dotK512(const short* hs, int lr, int kg,
                                        const s8v* wh, const s8v* wl,
                                        f4v& s0, f4v& s1)
{
    f4v a0h = {0.f, 0.f, 0.f, 0.f};
    f4v a0l = a0h, a1h = a0h, a1l = a0h;
    #pragma unroll
    for (int ks = 0; ks < 16; ++ks) {
        const short* p0 = hs + lr * 512 + ks * 32 + kg * 8;
        const short* p1 = hs + (16 + lr) * 512 + ks * 32 + kg * 8;
        union { u64 q[2]; s8v v; } A0, A1;
        A0.q[0] = cohload8(p0); A0.q[1] = cohload8(p0 + 4);
        A1.q[0] = cohload8(p1); A1.q[1] = cohload8(p1 + 4);
        a0h = mf16(A0.v, wh[ks], a0h);
        a0l = mf16(A0.v, wl[ks], a0l);
        a1h = mf16(A1.v, wh[ks], a1h);
        a1l = mf16(A1.v, wl[ks], a1l);
    }
    s0 = a0h + a0l;
    s1 = a1h + a1l;
}

// ---------------- prep kernels ---------------------------------------------
__global__ __launch_bounds__(256) void prep_dec(const float* __restrict__ dw,
                                                short* __restrict__ dbf)
{
    int id = blockIdx.x * 256 + threadIdx.x;
    if (id >= (NVOC * DIM) / 4) return;
    int e = id * 4;
    float4 v = *(const float4*)(dw + e);
    s4v o; o[0] = f2bf(v.x); o[1] = f2bf(v.y); o[2] = f2bf(v.z); o[3] = f2bf(v.w);
    *(s4v*)(dbf + e) = o;
}

__global__ __launch_bounds__(256) void prep_w0(const float* __restrict__ W0,
                                               short* __restrict__ w0h,
                                               short* __restrict__ w0l)
{
    int id = blockIdx.x * 256 + threadIdx.x;
    if (id >= 2048 * 512) return;
    float v = W0[id];
    short h = f2bf(v);
    w0h[id] = h;
    w0l[id] = f2bf(v - bf2f(h));
}

__global__ __launch_bounds__(256) void embed_k(const int* __restrict__ toks,
                                               const float* __restrict__ emb,
                                               short* __restrict__ xemb)
{
    int id = blockIdx.x * 256 + threadIdx.x;
    if (id >= (SEQ * BAT * DIM) / 4) return;
    int e  = id * 4;
    int tb = e >> 9;
    int k4 = e & 511;
    int tok = toks[tb];
    float4 v = *(const float4*)(emb + (size_t)tok * DIM + k4);
    s4v o; o[0] = f2bf(v.x); o[1] = f2bf(v.y); o[2] = f2bf(v.z); o[3] = f2bf(v.w);
    *(s4v*)(xemb + e) = o;
}

// zero h0 ring[8] + h1 ring[2] (each slot 32x512 bf16) + 96 flags
__global__ __launch_bounds__(256) void init_k(short* __restrict__ hbuf,
                                              unsigned* __restrict__ bar)
{
    int id = blockIdx.x * 256 + threadIdx.x;
    if (id < 10 * BAT * HID) hbuf[id] = 0;
    if (id < 96) bar[id] = 0;
}

// ---------------- Gx0 GEMM: [4096,2048] = xemb @ (W0hi+W0lo)^T, fp32 out ----
__global__ __launch_bounds__(256) void gx_gemm(
    const short* __restrict__ A,
    const short* __restrict__ Bh,
    const short* __restrict__ Bl,
    float* __restrict__ out)
{
    const int nb = blockIdx.x & 15, mb = blockIdx.x >> 4;
    const int m0 = mb * 128, n0 = nb * 128;
    __shared__ short Alds[128][40];
    __shared__ short Bhl[128][40];
    __shared__ short Bll[128][40];
    const int tid = threadIdx.x, l = tid & 63, w = tid >> 6;
    const int wr = w >> 1, wc = w & 1;
    const int lr = l & 15, kg = l >> 4;

    f4v acc[4][4];
    #pragma unroll
    for (int mi = 0; mi < 4; ++mi)
        #pragma unroll
        for (int ni = 0; ni < 4; ++ni) {
            acc[mi][ni][0] = 0.f; acc[mi][ni][1] = 0.f;
            acc[mi][ni][2] = 0.f; acc[mi][ni][3] = 0.f;
        }

    for (int kt = 0; kt < 16; ++kt) {
        #pragma unroll
        for (int i = 0; i < 2; ++i) {
            int c = tid + i * 256;
            int row = c >> 2, q = (c & 3) << 3;
            *(s8v*)&Alds[row][q] = *(const s8v*)(A  + (size_t)(m0 + row) * 512 + kt * 32 + q);
            *(s8v*)&Bhl[row][q]  = *(const s8v*)(Bh + (size_t)(n0 + row) * 512 + kt * 32 + q);
            *(s8v*)&Bll[row][q]  = *(const s8v*)(Bl + (size_t)(n0 + row) * 512 + kt * 32 + q);
        }
        __syncthreads();
        s8v af[4], bhf[4], blf[4];
        #pragma unroll
        for (int i = 0; i < 4; ++i) {
            af[i]  = *(const s8v*)&Alds[wr * 64 + i * 16 + lr][kg * 8];
            bhf[i] = *(const s8v*)&Bhl[wc * 64 + i * 16 + lr][kg * 8];
            blf[i] = *(const s8v*)&Bll[wc * 64 + i * 16 + lr][kg * 8];
        }
        #pragma unroll
        for (int mi = 0; mi < 4; ++mi)
            #pragma unroll
            for (int ni = 0; ni < 4; ++ni) {
                acc[mi][ni] = mf16(af[mi], bhf[ni], acc[mi][ni]);
                acc[mi][ni] = mf16(af[mi], blf[ni], acc[mi][ni]);
            }
        __syncthreads();
    }

    #pragma unroll
    for (int mi = 0; mi < 4; ++mi)
        #pragma unroll
        for (int ni = 0; ni < 4; ++ni) {
            int n = n0 + wc * 64 + ni * 16 + lr;
            #pragma unroll
            for (int r = 0; r < 4; ++r) {
                int m = m0 + wr * 64 + mi * 16 + kg * 4 + r;
                out[(size_t)m * 2048 + n] = acc[mi][ni][r];
            }
        }
}

// ---------------- persistent recurrence (3 roles x 32 blocks) ---------------
// role 0 (L0):  h0(t) = act(U0·h0(t-1) + Gx(t)); flags0[blk] = t+1
// role 1 (L1a): P(t)  = W1·h0(t) partials (raw frag layout); flags1a = t+1
// role 2 (L1b): h1(t) = act(U1·h1(t-1) + P(t)); adec(t); flags1 = t+1
// Wave w owns 16 rows = {g*512 + blk*16 + w*4 + q : g<4, q<4}.
// h0 ring depth 8, h1 depth 2, P depth 8. Polls:
//   L0 : flags0>=t (self, every step); [t%4==0] flags1>=t-4 (WAR, slack)
//   L1a: [t%4==0] flags0>=t+4, flags1>=t-4
//   L1b: [t%4==0] flags1a>=t+4; flags1>=t (self, every step)
__global__ __launch_bounds__(256, 1) void rnn_k(
    const float* __restrict__ W1f, const float* __restrict__ U0f,
    const float* __restrict__ U1f,
    const float* __restrict__ bias,
    const float* __restrict__ Gx,   // [4096][2048] fp32
    short* __restrict__ hbuf,       // h0[8][32][512] then h1[2][32][512]
    float* __restrict__ Pring,      // [8][32][4][64][8] fp32
    short* __restrict__ adec,       // [4096][512] bf16
    unsigned* __restrict__ bar)     // flags0[0..31] flags1a[32..63] flags1[64..95]
{
    const int tid  = threadIdx.x;
    const int bx   = blockIdx.x;
    const int role = bx >> 5;
    const int blk  = bx & 31;
    const int w    = tid >> 6;
    const int l    = tid & 63;
    const int lr   = l & 15;
    const int kg   = l >> 4;

    unsigned* flags0  = bar;
    unsigned* flags1a = bar + 32;
    unsigned* flags1  = bar + 64;

    __shared__ float S[4][16][33];            // per-wave gate transpose

    // --- one-time: weight fragments (16 rows x K512, hi/lo) -----------------
    const int grow = (lr >> 2) * 512 + blk * 16 + w * 4 + (lr & 3);
    const float* Wsrc = (role == 0) ? U0f : (role == 1 ? W1f : U1f);
    s8v wh[16], wl[16];
    #pragma unroll
    for (int ks = 0; ks < 16; ++ks) {
        const float* src = Wsrc + (size_t)grow * 512 + ks * 32 + kg * 8;
        float4 va = *(const float4*)src;
        float4 vb = *(const float4*)(src + 4);
        float vv[8] = {va.x, va.y, va.z, va.w, vb.x, vb.y, vb.z, vb.w};
        s8v hi, lo;
        #pragma unroll
        for (int e = 0; e < 8; ++e) {
            short h = f2bf(vv[e]);
            hi[e] = h; lo[e] = f2bf(vv[e] - bf2f(h));
        }
        wh[ks] = hi; wl[ks] = lo;
    }

    // epilogue lane mapping (roles 0/2): batch b, j-pair jj,jj+1
    const int b  = l & 31;
    const int jp = l >> 5;
    const int jj = blk * 16 + w * 4 + jp * 2;
    float bi0=0,bi1=0,bf0=0,bf1=0,bg0=0,bg1=0,bo0=0,bo1=0;
    if (role != 1) {
        bi0 = bias[jj];        bi1 = bias[jj + 1];
        bf0 = bias[512 + jj];  bf1 = bias[512 + jj + 1];
        bg0 = bias[1024 + jj]; bg1 = bias[1024 + jj + 1];
        bo0 = bias[1536 + jj]; bo1 = bias[1536 + jj + 1];
    }
    float c0 = 0.f, c1 = 0.f;

    short* h0r = hbuf;                        // [8][32][512]
    short* h1r = hbuf + 8 * BAT * HID;        // [2][32][512]

    for (int t = 0; t < SEQ; ++t) {
        const unsigned tu = (unsigned)t;

        if (role == 0) {
            // ---------------- L0 ----------------
            if ((t & 3) == 0 && t > 4) poll32s(flags1, l, tu - 4u);
            // Gx prefetch (plain cached, pre-poll)
            const float* gq = Gx + grow;
            float g0[4], g1[4];
            #pragma unroll
            for (int r = 0; r < 4; ++r) {
                g0[r] = gq[(size_t)(t * 32 + kg * 4 + r) * 2048];
                g1[r] = gq[(size_t)(t * 32 + 16 + kg * 4 + r) * 2048];
            }
            if (t > 0) poll32(flags0, l, tu);
            const short* hs = h0r + ((t + 7) & 7) * (BAT * HID);
            f4v s0, s1;
            dotK512(hs, lr, kg, wh, wl, s0, s1);
            #pragma unroll
            for (int r = 0; r < 4; ++r) {
                S[w][lr][kg * 4 + r]      = s0[r] + g0[r];
                S[w][lr][16 + kg * 4 + r] = s1[r] + g1[r];
            }
            asm volatile("s_waitcnt lgkmcnt(0)" ::: "memory");
            __builtin_amdgcn_sched_barrier(0);
            const int j0w = jp * 2, j1w = j0w + 1;
            float si0 = S[w][0 + j0w][b],  si1 = S[w][0 + j1w][b];
            float sf0 = S[w][4 + j0w][b],  sf1 = S[w][4 + j1w][b];
            float sg0 = S[w][8 + j0w][b],  sg1 = S[w][8 + j1w][b];
            float so0 = S[w][12 + j0w][b], so1 = S[w][12 + j1w][b];
            float gi0 = sigm(si0 + bi0), gi1 = sigm(si1 + bi1);
            float gf0 = sigm(sf0 + bf0), gf1 = sigm(sf1 + bf1);
            float gg0 = tanhf(sg0 + bg0), gg1 = tanhf(sg1 + bg1);
            float go0 = sigm(so0 + bo0), go1 = sigm(so1 + bo1);
            c0 = gf0 * c0 + gi0 * gg0;
            c1 = gf1 * c1 + gi1 * gg1;
            unsigned hw = (unsigned)(unsigned short)f2bf(go0 * tanhf(c0)) |
                          ((unsigned)(unsigned short)f2bf(go1 * tanhf(c1)) << 16);
            cohstore4(h0r + (t & 7) * (BAT * HID) + b * HID + jj, hw);
            asm volatile("s_waitcnt vmcnt(0)" ::: "memory");
            __syncthreads();
            if (tid == 0)
                __hip_atomic_store(flags0 + blk, tu + 1u,
                                   __ATOMIC_RELAXED, __HIP_MEMORY_SCOPE_AGENT);
        } else if (role == 1) {
            // ---------------- L1a ----------------
            if ((t & 3) == 0) {
                unsigned tgt = (tu + 4u > 128u) ? 128u : tu + 4u;
                poll32s(flags0, l, tgt);
                if (t > 4) poll32s(flags1, l, tu - 4u);
            }
            const short* hs = h0r + (t & 7) * (BAT * HID);   // h0(t)
            f4v s0, s1;
            dotK512(hs, lr, kg, wh, wl, s0, s1);
            float* pd = Pring + (size_t)(t & 7) * 65536 + blk * 2048 + w * 512 + l * 8;
            union { float f[2]; u64 q; } P;
            P.f[0] = s0[0]; P.f[1] = s0[1]; cohstore8(pd + 0, P.q);
            P.f[0] = s0[2]; P.f[1] = s0[3]; cohstore8(pd + 2, P.q);
            P.f[0] = s1[0]; P.f[1] = s1[1]; cohstore8(pd + 4, P.q);
            P.f[0] = s1[2]; P.f[1] = s1[3]; cohstore8(pd + 6, P.q);
            asm volatile("s_waitcnt vmcnt(0)" ::: "memory");
            __syncthreads();
            if (tid == 0)
                __hip_atomic_store(flags1a + blk, tu + 1u,
                                   __ATOMIC_RELAXED, __HIP_MEMORY_SCOPE_AGENT);
        } else {
            // ---------------- L1b ----------------
            if ((t & 3) == 0) {
                unsigned tgt = (tu + 4u > 128u) ? 128u : tu + 4u;
                poll32s(flags1a, l, tgt);
            }
            // P loads issued pre-poll (gated by the amortized flags1a check)
            const float* ps = Pring + (size_t)(t & 7) * 65536 + blk * 2048 + w * 512 + l * 8;
            u64 pq0 = cohload8(ps + 0), pq1 = cohload8(ps + 2);
            u64 pq2 = cohload8(ps + 4), pq3 = cohload8(ps + 6);
            if (t > 0) poll32(flags1, l, tu);
            const short* hs = h1r + ((t + 1) & 1) * (BAT * HID);  // h1(t-1)
            f4v s0, s1;
            dotK512(hs, lr, kg, wh, wl, s0, s1);
            union { u64 q; float f[2]; } P0, P1, P2, P3;
            P0.q = pq0; P1.q = pq1; P2.q = pq2; P3.q = pq3;
            S[w][lr][kg * 4 + 0]      = s0[0] + P0.f[0];
            S[w][lr][kg * 4 + 1]      = s0[1] + P0.f[1];
            S[w][lr][kg * 4 + 2]      = s0[2] + P1.f[0];
            S[w][lr][kg * 4 + 3]      = s0[3] + P1.f[1];
            S[w][lr][16 + kg * 4 + 0] = s1[0] + P2.f[0];
            S[w][lr][16 + kg * 4 + 1] = s1[1] + P2.f[1];
            S[w][lr][16 + kg * 4 + 2] = s1[2] + P3.f[0];
            S[w][lr][16 + kg * 4 + 3] = s1[3] + P3.f[1];
            asm volatile("s_waitcnt lgkmcnt(0)" ::: "memory");
            __builtin_amdgcn_sched_barrier(0);
            const int j0w = jp * 2, j1w = j0w + 1;
            float si0 = S[w][0 + j0w][b],  si1 = S[w][0 + j1w][b];
            float sf0 = S[w][4 + j0w][b],  sf1 = S[w][4 + j1w][b];
            float sg0 = S[w][8 + j0w][b],  sg1 = S[w][8 + j1w][b];
            float so0 = S[w][12 + j0w][b], so1 = S[w][12 + j1w][b];
            float gi0 = sigm(si0 + bi0), gi1 = sigm(si1 + bi1);
            float gf0 = sigm(sf0 + bf0), gf1 = sigm(sf1 + bf1);
            float gg0 = tanhf(sg0 + bg0), gg1 = tanhf(sg1 + bg1);
            float go0 = sigm(so0 + bo0), go1 = sigm(so1 + bo1);
            c0 = gf0 * c0 + gi0 * gg0;
            c1 = gf1 * c1 + gi1 * gg1;
            unsigned hw = (unsigned)(unsigned short)f2bf(go0 * tanhf(c0)) |
                          ((unsigned)(unsigned short)f2bf(go1 * tanhf(c1)) << 16);
            cohstore4(h1r + (t & 1) * (BAT * HID) + b * HID + jj, hw);
            asm volatile("s_waitcnt vmcnt(0)" ::: "memory");
            __syncthreads();
            if (tid == 0)
                __hip_atomic_store(flags1 + blk, tu + 1u,
                                   __ATOMIC_RELAXED, __HIP_MEMORY_SCOPE_AGENT);
            *(unsigned*)(adec + ((size_t)t * BAT + b) * HID + jj) = hw;
        }
    }
}

// ---------------- decoder GEMM ---------------------------------------------
__global__ __launch_bounds__(256) void dec_gemm(
    const short* __restrict__ A,
    const short* __restrict__ Bw,
    const float* __restrict__ bias,
    float* __restrict__ out)
{
    const int nb = blockIdx.x % 250, mb = blockIdx.x / 250;
    const int m0 = mb * 128, n0 = nb * 128;
    __shared__ short Alds[128][40];
    __shared__ short Blds[128][40];
    const int tid = threadIdx.x, l = tid & 63, w = tid >> 6;
    const int wr = w >> 1, wc = w & 1;
    const int lr = l & 15, kg = l >> 4;

    f4v acc[4][4];
    #pragma unroll
    for (int mi = 0; mi < 4; ++mi)
        #pragma unroll
        for (int ni = 0; ni < 4; ++ni) {
            acc[mi][ni][0] = 0.f; acc[mi][ni][1] = 0.f;
            acc[mi][ni][2] = 0.f; acc[mi][ni][3] = 0.f;
        }

    for (int kt = 0; kt < 16; ++kt) {
        #pragma unroll
        for (int i = 0; i < 2; ++i) {
            int c = tid + i * 256;
            int row = c >> 2, q = (c & 3) << 3;
            *(s8v*)&Alds[row][q] = *(const s8v*)(A  + (size_t)(m0 + row) * 512 + kt * 32 + q);
            *(s8v*)&Blds[row][q] = *(const s8v*)(Bw + (size_t)(n0 + row) * 512 + kt * 32 + q);
        }
        __syncthreads();
        s8v af[4], bfr[4];
        #pragma unroll
        for (int i = 0; i < 4; ++i) {
            af[i]  = *(const s8v*)&Alds[wr * 64 + i * 16 + lr][kg * 8];
            bfr[i] = *(const s8v*)&Blds[wc * 64 + i * 16 + lr][kg * 8];
        }
        #pragma unroll
        for (int mi = 0; mi < 4; ++mi)
            #pragma unroll
            for (int ni = 0; ni < 4; ++ni)
                acc[mi][ni] = mf16(af[mi], bfr[ni], acc[mi][ni]);
        __syncthreads();
    }

    #pragma unroll
    for (int mi = 0; mi < 4; ++mi)
        #pragma unroll
        for (int ni = 0; ni < 4; ++ni) {
            int n = n0 + wc * 64 + ni * 16 + lr;
            float bb = bias[n];
            #pragma unroll
            for (int r = 0; r < 4; ++r) {
                int m = m0 + wr * 64 + mi * 16 + kg * 4 + r;
                out[(size_t)m * NVOC + n] = acc[mi][ni][r] + bb;
            }
        }
}

extern "C" void kernel_launch(void* const* d_in, const int* in_sizes, int n_in,
                              void* d_out, int out_size, void* d_ws, size_t ws_size,
                              hipStream_t stream)
{
    const int*   toks = (const int*)d_in[0];
    const float* emb  = (const float*)d_in[1];
    const float* W0   = (const float*)d_in[2];
    const float* W1   = (const float*)d_in[3];
    const float* U0   = (const float*)d_in[4];
    const float* U1   = (const float*)d_in[5];
    const float* bias = (const float*)d_in[6];
    const float* dw   = (const float*)d_in[7];
    const float* db   = (const float*)d_in[8];
    float* out = (float*)d_out;

    char* ws = (char*)d_ws;
    size_t off = 0;
    auto alloc = [&](size_t bytes) -> void* {
        void* p = ws + off;
        off += (bytes + 255) & ~(size_t)255;
        return p;
    };
    short*    dbf   = (short*)alloc((size_t)NVOC * DIM * 2);
    short*    xemb  = (short*)alloc((size_t)SEQ * BAT * DIM * 2);
    short*    w0h   = (short*)alloc(2048ull * 512 * 2);
    short*    w0l   = (short*)alloc(2048ull * 512 * 2);
    float*    Gx    = (float*)alloc((size_t)SEQ * BAT * 2048 * 4);
    short*    hbuf  = (short*)alloc(10ull * BAT * HID * 2);
    float*    Pring = (float*)alloc(8ull * 65536 * 4);
    short*    adec  = (short*)alloc((size_t)SEQ * BAT * HID * 2);
    unsigned* bar   = (unsigned*)alloc(512);

    prep_dec<<<(NVOC * DIM / 4 + 255) / 256, 256, 0, stream>>>(dw, dbf);
    prep_w0 <<<(2048 * 512 + 255) / 256, 256, 0, stream>>>(W0, w0h, w0l);
    embed_k <<<(SEQ * BAT * DIM / 4 + 255) / 256, 256, 0, stream>>>(toks, emb, xemb);
    init_k  <<<(10 * BAT * HID + 255) / 256, 256, 0, stream>>>(hbuf, bar);

    gx_gemm<<<32 * 16, 256, 0, stream>>>(xemb, w0h, w0l, Gx);

    rnn_k<<<96, 256, 0, stream>>>(W1, U0, U1, bias, Gx, hbuf, Pring, adec, bar);

    dec_gemm<<<(SEQ * BAT / 128) * (NVOC / 128), 256, 0, stream>>>(adec, dbf, db, out);
}

// Round 10
// 979.666 us; speedup vs baseline: 2.4050x; 2.4050x over previous
//
#include <hip/hip_runtime.h>
#include <hip/hip_bf16.h>

// ---------------------------------------------------------------------------
// LSTM LM forward on MI355X — round 10 (round-8 base + serial-path cuts).
// Persistent rnn_k: 64 blocks x 512 threads, K-split wave pairs, 128 VGPR
// weight fragments, h0 ring depth 8, h1 depth 2, per-block flag stores.
// NEW vs r8: single combined poll per step (L0: flags0>=it & flags1>=it-6;
// L1: flags0>=it & flags1>=it), issue-then-commit staging (all coherent
// loads in flight before LDS writes), no-sleep hot polls.
// ---------------------------------------------------------------------------

#define NVOC 32000
#define DIM  512
#define HID  512
#define SEQ  128
#define BAT  32
#define NB   64      // blocks in persistent kernel (32 per layer)

typedef short s8v __attribute__((ext_vector_type(8)));
typedef short s4v __attribute__((ext_vector_type(4)));
typedef float f4v __attribute__((ext_vector_type(4)));
typedef unsigned long long u64;

__device__ __forceinline__ short f2bf(float f) {
    unsigned u = __builtin_bit_cast(unsigned, f);
    unsigned r = (u + 0x7fffu + ((u >> 16) & 1u)) >> 16;
    return (short)r;
}
__device__ __forceinline__ float bf2f(short s) {
    unsigned u = ((unsigned)(unsigned short)s) << 16;
    return __builtin_bit_cast(float, u);
}
__device__ __forceinline__ float sigm(float x) { return 1.f / (1.f + __expf(-x)); }

__device__ __forceinline__ f4v mf16(s8v a, s8v b, f4v c) {
    return __builtin_amdgcn_mfma_f32_16x16x32_bf16(a, b, c, 0, 0, 0);
}

// coherent (cross-XCD) loads/stores, bypassing L1+L2
__device__ __forceinline__ u64 cohload8(const short* p) {
    return __hip_atomic_load((const u64*)p, __ATOMIC_RELAXED,
                             __HIP_MEMORY_SCOPE_AGENT);
}
__device__ __forceinline__ void cohstore2(short* p, unsigned short v) {
    __hip_atomic_store((unsigned short*)p, v, __ATOMIC_RELAXED,
                       __HIP_MEMORY_SCOPE_AGENT);
}

// combined poll (one wave): lane<32 checks flags0[l]>=tA, lane>=32 flags1[l-32]>=tB
__device__ __forceinline__ void pollwait(const unsigned* bar, int l,
                                         unsigned tA, unsigned tB) {
    const unsigned* fp = bar + l;
    const unsigned tgt = (l < 32) ? tA : tB;
    while (true) {
        unsigned v = __hip_atomic_load(fp, __ATOMIC_RELAXED,
                                       __HIP_MEMORY_SCOPE_AGENT);
        if (__all((int)(v >= tgt))) break;
    }
}

// ---------------- prep kernels ---------------------------------------------
__global__ __launch_bounds__(256) void prep_dec(const float* __restrict__ dw,
                                                short* __restrict__ dbf)
{
    int id = blockIdx.x * 256 + threadIdx.x;          // x4 elems
    if (id >= (NVOC * DIM) / 4) return;
    int e = id * 4;
    float4 v = *(const float4*)(dw + e);
    s4v o; o[0] = f2bf(v.x); o[1] = f2bf(v.y); o[2] = f2bf(v.z); o[3] = f2bf(v.w);
    *(s4v*)(dbf + e) = o;
}

// split W0 fp32 -> hi/lo bf16 (for the Gx GEMM)
__global__ __launch_bounds__(256) void prep_w0(const float* __restrict__ W0,
                                               short* __restrict__ w0h,
                                               short* __restrict__ w0l)
{
    int id = blockIdx.x * 256 + threadIdx.x;          // 2048*512
    if (id >= 2048 * 512) return;
    float v = W0[id];
    short h = f2bf(v);
    w0h[id] = h;
    w0l[id] = f2bf(v - bf2f(h));
}

// xemb[t*32+b][512] bf16
__global__ __launch_bounds__(256) void embed_k(const int* __restrict__ toks,
                                               const float* __restrict__ emb,
                                               short* __restrict__ xemb)
{
    int id = blockIdx.x * 256 + threadIdx.x;          // x4 elems over 4096*512
    if (id >= (SEQ * BAT * DIM) / 4) return;
    int e  = id * 4;
    int tb = e >> 9;
    int k4 = e & 511;
    int tok = toks[tb];
    float4 v = *(const float4*)(emb + (size_t)tok * DIM + k4);
    s4v o; o[0] = f2bf(v.x); o[1] = f2bf(v.y); o[2] = f2bf(v.z); o[3] = f2bf(v.w);
    *(s4v*)(xemb + e) = o;
}

// zero h rings: h0[8][32][512] + h1[2][32][512] = 10 slots; + flags
__global__ __launch_bounds__(256) void init_k(short* __restrict__ hbuf,
                                              unsigned* __restrict__ bar)
{
    int id = blockIdx.x * 256 + threadIdx.x;
    if (id < 10 * BAT * HID) hbuf[id] = 0;
    if (id < 64) bar[id] = 0;
}

// ---------------- Gx0 GEMM: [4096,2048] = xemb @ (W0hi+W0lo)^T, fp32 out ----
__global__ __launch_bounds__(256) void gx_gemm(
    const short* __restrict__ A,    // xemb [4096][512] bf16
    const short* __restrict__ Bh,   // w0hi [2048][512] bf16
    const short* __restrict__ Bl,   // w0lo [2048][512] bf16
    float* __restrict__ out)        // Gx  [4096][2048] fp32
{
    const int nb = blockIdx.x & 15, mb = blockIdx.x >> 4;
    const int m0 = mb * 128, n0 = nb * 128;
    __shared__ short Alds[128][40];
    __shared__ short Bhl[128][40];
    __shared__ short Bll[128][40];
    const int tid = threadIdx.x, l = tid & 63, w = tid >> 6;
    const int wr = w >> 1, wc = w & 1;
    const int lr = l & 15, kg = l >> 4;

    f4v acc[4][4];
    #pragma unroll
    for (int mi = 0; mi < 4; ++mi)
        #pragma unroll
        for (int ni = 0; ni < 4; ++ni) {
            acc[mi][ni][0] = 0.f; acc[mi][ni][1] = 0.f;
            acc[mi][ni][2] = 0.f; acc[mi][ni][3] = 0.f;
        }

    for (int kt = 0; kt < 16; ++kt) {
        #pragma unroll
        for (int i = 0; i < 2; ++i) {
            int c = tid + i * 256;
            int row = c >> 2, q = (c & 3) << 3;
            *(s8v*)&Alds[row][q] = *(const s8v*)(A  + (size_t)(m0 + row) * 512 + kt * 32 + q);
            *(s8v*)&Bhl[row][q]  = *(const s8v*)(Bh + (size_t)(n0 + row) * 512 + kt * 32 + q);
            *(s8v*)&Bll[row][q]  = *(const s8v*)(Bl + (size_t)(n0 + row) * 512 + kt * 32 + q);
        }
        __syncthreads();
        s8v af[4], bhf[4], blf[4];
        #pragma unroll
        for (int i = 0; i < 4; ++i) {
            af[i]  = *(const s8v*)&Alds[wr * 64 + i * 16 + lr][kg * 8];
            bhf[i] = *(const s8v*)&Bhl[wc * 64 + i * 16 + lr][kg * 8];
            blf[i] = *(const s8v*)&Bll[wc * 64 + i * 16 + lr][kg * 8];
        }
        #pragma unroll
        for (int mi = 0; mi < 4; ++mi)
            #pragma unroll
            for (int ni = 0; ni < 4; ++ni) {
                acc[mi][ni] = mf16(af[mi], bhf[ni], acc[mi][ni]);
                acc[mi][ni] = mf16(af[mi], blf[ni], acc[mi][ni]);
            }
        __syncthreads();
    }

    #pragma unroll
    for (int mi = 0; mi < 4; ++mi)
        #pragma unroll
        for (int ni = 0; ni < 4; ++ni) {
            int n = n0 + wc * 64 + ni * 16 + lr;
            #pragma unroll
            for (int r = 0; r < 4; ++r) {
                int m = m0 + wr * 64 + mi * 16 + kg * 4 + r;
                out[(size_t)m * 2048 + n] = acc[mi][ni][r];
            }
        }
}

// ---------------- persistent recurrence ------------------------------------
// 64 blocks x 512 threads (8 waves). Block bl: layer=bl>>5, j0=(bl&31)*16.
// Wave w2: gate g=w2&3, K-half kh=w2>>2.
// h0 ring depth 8: write it&7, read (it-1)&7. h1: write (it+1)&1, read it&1.
// Polls (combined, one per step):
//   L0: flags0>=it (self RAW), flags1>=it-6 (h0-slot WAR, ring depth 8)
//   L1: flags0>=it (h0 RAW),   flags1>=it (h1 chain RAW+WAR)
__global__ __launch_bounds__(512, 1) void rnn_k(
    const float* __restrict__ W1f, const float* __restrict__ U0f,
    const float* __restrict__ U1f,
    const float* __restrict__ bias,
    const float* __restrict__ Gx,   // [4096][2048] fp32
    short* __restrict__ hbuf,       // h0[8][32][512] then h1[2][32][512]
    short* __restrict__ adec,       // [128*32][512] bf16
    unsigned* __restrict__ bar)     // flags0[0..31], flags1[32..63]
{
    const int tid   = threadIdx.x;
    const int bl    = blockIdx.x;
    const int layer = bl >> 5;
    const int j0    = (bl & 31) * 16;
    const int w2    = tid >> 6;       // 0..7
    const int g     = w2 & 3;         // gate
    const int kh    = w2 >> 2;        // K-half
    const int l     = tid & 63;
    const int lr    = l & 15;
    const int kg    = l >> 4;

    __shared__ short Alds[32][1032];
    __shared__ float gbuf[2][4][16][33];      // [kh][gate][j][batch(+pad)]

    // --- one-time: weight slice fp32 -> hi/lo bf16 fragments in VGPRs -------
    const int gr = g * 512 + j0 + lr;         // gate-row in [0,2048)
    s8v wh[16], wlo[16];
    if (layer == 0) {
        #pragma unroll
        for (int ks = 0; ks < 8; ++ks) {
            const float* src = U0f + (size_t)gr * 512 + kh * 256 + ks * 32 + kg * 8;
            float4 va = *(const float4*)src;
            float4 vb = *(const float4*)(src + 4);
            float vv[8] = {va.x, va.y, va.z, va.w, vb.x, vb.y, vb.z, vb.w};
            s8v hi, lo;
            #pragma unroll
            for (int e = 0; e < 8; ++e) {
                short h = f2bf(vv[e]);
                hi[e] = h; lo[e] = f2bf(vv[e] - bf2f(h));
            }
            wh[ks] = hi; wlo[ks] = lo;
        }
    } else {
        const float* base = kh ? U1f : W1f;   // kh=0: W1 (vs h0), kh=1: U1 (vs h1)
        #pragma unroll
        for (int ks = 0; ks < 16; ++ks) {
            const float* src = base + (size_t)gr * 512 + ks * 32 + kg * 8;
            float4 va = *(const float4*)src;
            float4 vb = *(const float4*)(src + 4);
            float vv[8] = {va.x, va.y, va.z, va.w, vb.x, vb.y, vb.z, vb.w};
            s8v hi, lo;
            #pragma unroll
            for (int e = 0; e < 8; ++e) {
                short h = f2bf(vv[e]);
                hi[e] = h; lo[e] = f2bf(vv[e] - bf2f(h));
            }
            wh[ks] = hi; wlo[ks] = lo;
        }
    }

    // --- epilogue ownership: thread -> (batch eb, single j = j0+ej) ---------
    const int eb = tid >> 4;                  // 0..31
    const int ej = tid & 15;                  // 0..15
    const int jj = j0 + ej;
    const float bi = bias[jj];
    const float bf_ = bias[512 + jj];
    const float bg = bias[1024 + jj];
    const float bo = bias[1536 + jj];
    float cst = 0.f;

    short* h0r = hbuf;                        // [8][32][512]
    short* h1r = hbuf + 8 * BAT * HID;        // [2][32][512]

    for (int it = 0; it <= SEQ; ++it) {
        const bool active = (layer == 0) ? (it < SEQ) : (it >= 1);
        const unsigned itu = (unsigned)it;
        const int s0w = it & 7;               // h0 write slot
        const int s0r = (it + 7) & 7;         // h0 read slot  (it-1)
        const int s1w = (it + 1) & 1;         // h1 write slot (it-1)
        const int s1r = it & 1;               // h1 read slot  (it-2)

        if (layer == 0) {
            // prefetch Gx (cached) before any wait
            float gx0 = 0.f, gx1 = 0.f, gx2 = 0.f, gx3 = 0.f;
            if (active) {
                const float* gp = Gx + ((size_t)it * BAT + eb) * 2048 + jj;
                gx0 = gp[0]; gx1 = gp[512]; gx2 = gp[1024]; gx3 = gp[1536];
            }
            // combined poll: self RAW + WAR slack
            if (it > 0) {
                if (w2 == 0) pollwait(bar, l, itu,
                                      (it >= 7) ? itu - 6u : 0u);
                __syncthreads();
            }
            if (active) {
                const short* s = h0r + s0r * BAT * HID;   // h0(it-1)
                u64 va[8];
                #pragma unroll
                for (int i = 0; i < 8; ++i) {
                    int c = tid + i * 512;
                    va[i] = cohload8(s + (c >> 7) * HID + (c & 127) * 4);
                }
                #pragma unroll
                for (int i = 0; i < 8; ++i) {
                    int c = tid + i * 512;
                    *(u64*)&Alds[c >> 7][(c & 127) * 4] = va[i];
                }
            }
            __syncthreads();
            if (active) {
                f4v a0h, a0l, a1h, a1l;
                a0h[0]=0.f; a0h[1]=0.f; a0h[2]=0.f; a0h[3]=0.f;
                a0l = a0h; a1h = a0h; a1l = a0h;
                #pragma unroll
                for (int ks = 0; ks < 8; ++ks) {
                    const int k = kh * 256 + ks * 32 + kg * 8;
                    s8v a0 = *(const s8v*)&Alds[lr][k];
                    s8v a1 = *(const s8v*)&Alds[16 + lr][k];
                    a0h = mf16(a0, wh[ks],  a0h);
                    a0l = mf16(a0, wlo[ks], a0l);
                    a1h = mf16(a1, wh[ks],  a1h);
                    a1l = mf16(a1, wlo[ks], a1l);
                }
                #pragma unroll
                for (int r = 0; r < 4; ++r) {
                    gbuf[kh][g][lr][kg * 4 + r]      = a0h[r] + a0l[r];
                    gbuf[kh][g][lr][16 + kg * 4 + r] = a1h[r] + a1l[r];
                }
            }
            __syncthreads();
            unsigned short hs = 0;
            if (active) {
                float si = gbuf[0][0][ej][eb] + gbuf[1][0][ej][eb] + gx0;
                float sf = gbuf[0][1][ej][eb] + gbuf[1][1][ej][eb] + gx1;
                float sg = gbuf[0][2][ej][eb] + gbuf[1][2][ej][eb] + gx2;
                float so = gbuf[0][3][ej][eb] + gbuf[1][3][ej][eb] + gx3;
                float gi = sigm(si + bi);
                float gf = sigm(sf + bf_);
                float gg = tanhf(sg + bg);
                float go = sigm(so + bo);
                cst = gf * cst + gi * gg;
                hs = (unsigned short)f2bf(go * tanhf(cst));
                cohstore2(h0r + s0w * BAT * HID + eb * HID + jj, hs);
            }
            if (it < SEQ) {
                asm volatile("s_waitcnt vmcnt(0)" ::: "memory");
                __syncthreads();
                if (tid == 0)
                    __hip_atomic_store(bar + (bl & 31), itu + 1u,
                                       __ATOMIC_RELAXED, __HIP_MEMORY_SCOPE_AGENT);
            }
        } else {
            // ---- layer 1 ----
            // combined poll: h0 RAW + h1 chain
            if (it > 0) {
                if (w2 == 0) pollwait(bar, l, itu, itu);
                __syncthreads();
            }
            if (active) {
                const short* sA = h0r + s0r * BAT * HID;  // h0(it-1)
                const short* sB = h1r + s1r * BAT * HID;  // h1(it-2)
                u64 va[8], vb[8];
                #pragma unroll
                for (int i = 0; i < 8; ++i) {
                    int c = tid + i * 512;
                    va[i] = cohload8(sA + (c >> 7) * HID + (c & 127) * 4);
                }
                #pragma unroll
                for (int i = 0; i < 8; ++i) {
                    int c = tid + i * 512;
                    vb[i] = cohload8(sB + (c >> 7) * HID + (c & 127) * 4);
                }
                #pragma unroll
                for (int i = 0; i < 8; ++i) {
                    int c = tid + i * 512;
                    *(u64*)&Alds[c >> 7][(c & 127) * 4] = va[i];
                }
                #pragma unroll
                for (int i = 0; i < 8; ++i) {
                    int c = tid + i * 512;
                    *(u64*)&Alds[c >> 7][512 + (c & 127) * 4] = vb[i];
                }
            }
            __syncthreads();
            if (active) {
                f4v a0h, a0l, a1h, a1l;
                a0h[0]=0.f; a0h[1]=0.f; a0h[2]=0.f; a0h[3]=0.f;
                a0l = a0h; a1h = a0h; a1l = a0h;
                #pragma unroll
                for (int ks = 0; ks < 16; ++ks) {
                    const int k = kh * 512 + ks * 32 + kg * 8;
                    s8v a0 = *(const s8v*)&Alds[lr][k];
                    s8v a1 = *(const s8v*)&Alds[16 + lr][k];
                    a0h = mf16(a0, wh[ks],  a0h);
                    a0l = mf16(a0, wlo[ks], a0l);
                    a1h = mf16(a1, wh[ks],  a1h);
                    a1l = mf16(a1, wlo[ks], a1l);
                }
                #pragma unroll
                for (int r = 0; r < 4; ++r) {
                    gbuf[kh][g][lr][kg * 4 + r]      = a0h[r] + a0l[r];
                    gbuf[kh][g][lr][16 + kg * 4 + r] = a1h[r] + a1l[r];
                }
            }
            __syncthreads();
            unsigned short hs = 0;
            if (active) {
                float si = gbuf[0][0][ej][eb] + gbuf[1][0][ej][eb];
                float sf = gbuf[0][1][ej][eb] + gbuf[1][1][ej][eb];
                float sg = gbuf[0][2][ej][eb] + gbuf[1][2][ej][eb];
                float so = gbuf[0][3][ej][eb] + gbuf[1][3][ej][eb];
                float gi = sigm(si + bi);
                float gf = sigm(sf + bf_);
                float gg = tanhf(sg + bg);
                float go = sigm(so + bo);
                cst = gf * cst + gi * gg;
                hs = (unsigned short)f2bf(go * tanhf(cst));
                cohstore2(h1r + s1w * BAT * HID + eb * HID + jj, hs);
            }
            if (it < SEQ) {
                asm volatile("s_waitcnt vmcnt(0)" ::: "memory");
                __syncthreads();
                if (tid == 0)
                    __hip_atomic_store(bar + 32 + (bl & 31), itu + 1u,
                                       __ATOMIC_RELAXED, __HIP_MEMORY_SCOPE_AGENT);
            }
            if (active)
                adec[((size_t)(it - 1) * BAT + eb) * HID + jj] = (short)hs;
        }
    }
}

// ---------------- decoder GEMM ---------------------------------------------
__global__ __launch_bounds__(256) void dec_gemm(
    const short* __restrict__ A,    // [4096][512] bf16
    const short* __restrict__ Bw,   // [32000][512] bf16
    const float* __restrict__ bias, // [32000]
    float* __restrict__ out)        // [4096][32000]
{
    const int nb = blockIdx.x % 250, mb = blockIdx.x / 250;
    const int m0 = mb * 128, n0 = nb * 128;
    __shared__ short Alds[128][40];
    __shared__ short Blds[128][40];
    const int tid = threadIdx.x, l = tid & 63, w = tid >> 6;
    const int wr = w >> 1, wc = w & 1;
    const int lr = l & 15, kg = l >> 4;

    f4v acc[4][4];
    #pragma unroll
    for (int mi = 0; mi < 4; ++mi)
        #pragma unroll
        for (int ni = 0; ni < 4; ++ni) {
            acc[mi][ni][0] = 0.f; acc[mi][ni][1] = 0.f;
            acc[mi][ni][2] = 0.f; acc[mi][ni][3] = 0.f;
        }

    for (int kt = 0; kt < 16; ++kt) {
        #pragma unroll
        for (int i = 0; i < 2; ++i) {
            int c = tid + i * 256;
            int row = c >> 2, q = (c & 3) << 3;
            *(s8v*)&Alds[row][q] = *(const s8v*)(A  + (size_t)(m0 + row) * 512 + kt * 32 + q);
            *(s8v*)&Blds[row][q] = *(const s8v*)(Bw + (size_t)(n0 + row) * 512 + kt * 32 + q);
        }
        __syncthreads();
        s8v af[4], bfr[4];
        #pragma unroll
        for (int i = 0; i < 4; ++i) {
            af[i]  = *(const s8v*)&Alds[wr * 64 + i * 16 + lr][kg * 8];
            bfr[i] = *(const s8v*)&Blds[wc * 64 + i * 16 + lr][kg * 8];
        }
        #pragma unroll
        for (int mi = 0; mi < 4; ++mi)
            #pragma unroll
            for (int ni = 0; ni < 4; ++ni)
                acc[mi][ni] = mf16(af[mi], bfr[ni], acc[mi][ni]);
        __syncthreads();
    }

    #pragma unroll
    for (int mi = 0; mi < 4; ++mi)
        #pragma unroll
        for (int ni = 0; ni < 4; ++ni) {
            int n = n0 + wc * 64 + ni * 16 + lr;
            float bb = bias[n];
            #pragma unroll
            for (int r = 0; r < 4; ++r) {
                int m = m0 + wr * 64 + mi * 16 + kg * 4 + r;
                out[(size_t)m * NVOC + n] = acc[mi][ni][r] + bb;
            }
        }
}

extern "C" void kernel_launch(void* const* d_in, const int* in_sizes, int n_in,
                              void* d_out, int out_size, void* d_ws, size_t ws_size,
                              hipStream_t stream)
{
    const int*   toks = (const int*)d_in[0];
    const float* emb  = (const float*)d_in[1];
    const float* W0   = (const float*)d_in[2];
    const float* W1   = (const float*)d_in[3];
    const float* U0   = (const float*)d_in[4];
    const float* U1   = (const float*)d_in[5];
    const float* bias = (const float*)d_in[6];
    const float* dw   = (const float*)d_in[7];
    const float* db   = (const float*)d_in[8];
    float* out = (float*)d_out;

    char* ws = (char*)d_ws;
    size_t off = 0;
    auto alloc = [&](size_t bytes) -> void* {
        void* p = ws + off;
        off += (bytes + 255) & ~(size_t)255;
        return p;
    };
    short*    dbf  = (short*)alloc((size_t)NVOC * DIM * 2);
    short*    xemb = (short*)alloc((size_t)SEQ * BAT * DIM * 2);
    short*    w0h  = (short*)alloc(2048ull * 512 * 2);
    short*    w0l  = (short*)alloc(2048ull * 512 * 2);
    float*    Gx   = (float*)alloc((size_t)SEQ * BAT * 2048 * 4);
    short*    hbuf = (short*)alloc(10ull * BAT * HID * 2);
    short*    adec = (short*)alloc((size_t)SEQ * BAT * HID * 2);
    unsigned* bar  = (unsigned*)alloc(256);

    prep_dec<<<(NVOC * DIM / 4 + 255) / 256, 256, 0, stream>>>(dw, dbf);
    prep_w0 <<<(2048 * 512 + 255) / 256, 256, 0, stream>>>(W0, w0h, w0l);
    embed_k <<<(SEQ * BAT * DIM / 4 + 255) / 256, 256, 0, stream>>>(toks, emb, xemb);
    init_k  <<<(10 * BAT * HID + 255) / 256, 256, 0, stream>>>(hbuf, bar);

    gx_gemm<<<32 * 16, 256, 0, stream>>>(xemb, w0h, w0l, Gx);

    rnn_k<<<NB, 512, 0, stream>>>(W1, U0, U1, bias, Gx, hbuf, adec, bar);

    dec_gemm<<<(SEQ * BAT / 128) * (NVOC / 128), 256, 0, stream>>>(adec, dbf, db, out);
}

// Round 11
// 871.279 us; speedup vs baseline: 2.7042x; 1.1244x over previous
//
#include <hip/hip_runtime.h>
#include <hip/hip_bf16.h>

// ---------------------------------------------------------------------------
// LSTM LM forward on MI355X — round 11 (round-10 + fused decoder role).
// Persistent kernel, 256 blocks x 512 threads:
//   blocks 0..31  : L0 recurrence (U0·h, Gx hoisted)
//   blocks 32..63 : L1 recurrence (W1·h0 + U1·h1)
//   blocks 64..255: decoder (128x128 tiles, gated on flags1 >= 4*mb+5)
// adec written write-through BEFORE the flag publish; decoder overlaps the
// recurrence on the otherwise-idle 192 CUs.
// ---------------------------------------------------------------------------

#define NVOC 32000
#define DIM  512
#define HID  512
#define SEQ  128
#define BAT  32
#define NB   64      // recurrence blocks (32 per layer)
#define NDEC 192     // decoder blocks
#define NTILE (32 * 250)

typedef short s8v __attribute__((ext_vector_type(8)));
typedef short s4v __attribute__((ext_vector_type(4)));
typedef float f4v __attribute__((ext_vector_type(4)));
typedef unsigned long long u64;

__device__ __forceinline__ short f2bf(float f) {
    unsigned u = __builtin_bit_cast(unsigned, f);
    unsigned r = (u + 0x7fffu + ((u >> 16) & 1u)) >> 16;
    return (short)r;
}
__device__ __forceinline__ float bf2f(short s) {
    unsigned u = ((unsigned)(unsigned short)s) << 16;
    return __builtin_bit_cast(float, u);
}
__device__ __forceinline__ float sigm(float x) { return 1.f / (1.f + __expf(-x)); }

__device__ __forceinline__ f4v mf16(s8v a, s8v b, f4v c) {
    return __builtin_amdgcn_mfma_f32_16x16x32_bf16(a, b, c, 0, 0, 0);
}

// coherent (cross-XCD) loads/stores, bypassing L1+L2
__device__ __forceinline__ u64 cohload8(const short* p) {
    return __hip_atomic_load((const u64*)p, __ATOMIC_RELAXED,
                             __HIP_MEMORY_SCOPE_AGENT);
}
__device__ __forceinline__ void cohstore2(short* p, unsigned short v) {
    __hip_atomic_store((unsigned short*)p, v, __ATOMIC_RELAXED,
                       __HIP_MEMORY_SCOPE_AGENT);
}

// combined poll (one wave): lane<32 checks flags0[l]>=tA, lane>=32 flags1[l-32]>=tB
__device__ __forceinline__ void pollwait(const unsigned* bar, int l,
                                         unsigned tA, unsigned tB) {
    const unsigned* fp = bar + l;
    const unsigned tgt = (l < 32) ? tA : tB;
    while (true) {
        unsigned v = __hip_atomic_load(fp, __ATOMIC_RELAXED,
                                       __HIP_MEMORY_SCOPE_AGENT);
        if (__all((int)(v >= tgt))) break;
    }
}
// 32-flag sleep-poll (decoder)
__device__ __forceinline__ void poll32s(const unsigned* f, int l, unsigned tgt) {
    const unsigned* p = f + (l & 31);
    while (true) {
        unsigned v = __hip_atomic_load(p, __ATOMIC_RELAXED,
                                       __HIP_MEMORY_SCOPE_AGENT);
        if (__all((int)(v >= tgt))) break;
        __builtin_amdgcn_s_sleep(2);
    }
}

// ---------------- prep kernels ---------------------------------------------
__global__ __launch_bounds__(256) void prep_dec(const float* __restrict__ dw,
                                                short* __restrict__ dbf)
{
    int id = blockIdx.x * 256 + threadIdx.x;          // x4 elems
    if (id >= (NVOC * DIM) / 4) return;
    int e = id * 4;
    float4 v = *(const float4*)(dw + e);
    s4v o; o[0] = f2bf(v.x); o[1] = f2bf(v.y); o[2] = f2bf(v.z); o[3] = f2bf(v.w);
    *(s4v*)(dbf + e) = o;
}

__global__ __launch_bounds__(256) void prep_w0(const float* __restrict__ W0,
                                               short* __restrict__ w0h,
                                               short* __restrict__ w0l)
{
    int id = blockIdx.x * 256 + threadIdx.x;          // 2048*512
    if (id >= 2048 * 512) return;
    float v = W0[id];
    short h = f2bf(v);
    w0h[id] = h;
    w0l[id] = f2bf(v - bf2f(h));
}

__global__ __launch_bounds__(256) void embed_k(const int* __restrict__ toks,
                                               const float* __restrict__ emb,
                                               short* __restrict__ xemb)
{
    int id = blockIdx.x * 256 + threadIdx.x;          // x4 elems over 4096*512
    if (id >= (SEQ * BAT * DIM) / 4) return;
    int e  = id * 4;
    int tb = e >> 9;
    int k4 = e & 511;
    int tok = toks[tb];
    float4 v = *(const float4*)(emb + (size_t)tok * DIM + k4);
    s4v o; o[0] = f2bf(v.x); o[1] = f2bf(v.y); o[2] = f2bf(v.z); o[3] = f2bf(v.w);
    *(s4v*)(xemb + e) = o;
}

__global__ __launch_bounds__(256) void init_k(short* __restrict__ hbuf,
                                              unsigned* __restrict__ bar)
{
    int id = blockIdx.x * 256 + threadIdx.x;
    if (id < 10 * BAT * HID) hbuf[id] = 0;
    if (id < 64) bar[id] = 0;
}

// ---------------- Gx0 GEMM: [4096,2048] = xemb @ (W0hi+W0lo)^T, fp32 out ----
__global__ __launch_bounds__(256) void gx_gemm(
    const short* __restrict__ A,
    const short* __restrict__ Bh,
    const short* __restrict__ Bl,
    float* __restrict__ out)
{
    const int nb = blockIdx.x & 15, mb = blockIdx.x >> 4;
    const int m0 = mb * 128, n0 = nb * 128;
    __shared__ short Alds[128][40];
    __shared__ short Bhl[128][40];
    __shared__ short Bll[128][40];
    const int tid = threadIdx.x, l = tid & 63, w = tid >> 6;
    const int wr = w >> 1, wc = w & 1;
    const int lr = l & 15, kg = l >> 4;

    f4v acc[4][4];
    #pragma unroll
    for (int mi = 0; mi < 4; ++mi)
        #pragma unroll
        for (int ni = 0; ni < 4; ++ni) {
            acc[mi][ni][0] = 0.f; acc[mi][ni][1] = 0.f;
            acc[mi][ni][2] = 0.f; acc[mi][ni][3] = 0.f;
        }

    for (int kt = 0; kt < 16; ++kt) {
        #pragma unroll
        for (int i = 0; i < 2; ++i) {
            int c = tid + i * 256;
            int row = c >> 2, q = (c & 3) << 3;
            *(s8v*)&Alds[row][q] = *(const s8v*)(A  + (size_t)(m0 + row) * 512 + kt * 32 + q);
            *(s8v*)&Bhl[row][q]  = *(const s8v*)(Bh + (size_t)(n0 + row) * 512 + kt * 32 + q);
            *(s8v*)&Bll[row][q]  = *(const s8v*)(Bl + (size_t)(n0 + row) * 512 + kt * 32 + q);
        }
        __syncthreads();
        s8v af[4], bhf[4], blf[4];
        #pragma unroll
        for (int i = 0; i < 4; ++i) {
            af[i]  = *(const s8v*)&Alds[wr * 64 + i * 16 + lr][kg * 8];
            bhf[i] = *(const s8v*)&Bhl[wc * 64 + i * 16 + lr][kg * 8];
            blf[i] = *(const s8v*)&Bll[wc * 64 + i * 16 + lr][kg * 8];
        }
        #pragma unroll
        for (int mi = 0; mi < 4; ++mi)
            #pragma unroll
            for (int ni = 0; ni < 4; ++ni) {
                acc[mi][ni] = mf16(af[mi], bhf[ni], acc[mi][ni]);
                acc[mi][ni] = mf16(af[mi], blf[ni], acc[mi][ni]);
            }
        __syncthreads();
    }

    #pragma unroll
    for (int mi = 0; mi < 4; ++mi)
        #pragma unroll
        for (int ni = 0; ni < 4; ++ni) {
            int n = n0 + wc * 64 + ni * 16 + lr;
            #pragma unroll
            for (int r = 0; r < 4; ++r) {
                int m = m0 + wr * 64 + mi * 16 + kg * 4 + r;
                out[(size_t)m * 2048 + n] = acc[mi][ni][r];
            }
        }
}

// ---------------- fused persistent recurrence + decoder ---------------------
__global__ __launch_bounds__(512, 1) void rnn_k(
    const float* __restrict__ W1f, const float* __restrict__ U0f,
    const float* __restrict__ U1f,
    const float* __restrict__ bias,
    const float* __restrict__ Gx,   // [4096][2048] fp32
    short* __restrict__ hbuf,       // h0[8][32][512] then h1[2][32][512]
    short* __restrict__ adec,       // [4096][512] bf16 (write-through)
    const short* __restrict__ dbf,  // dec_w bf16 [32000][512]
    const float* __restrict__ db,   // dec bias [32000]
    float* __restrict__ out,        // [4096][32000]
    unsigned* __restrict__ bar)     // flags0[0..31], flags1[32..63]
{
    const int tid = threadIdx.x;
    const int bx  = blockIdx.x;
    const int w2  = tid >> 6;
    const int l   = tid & 63;
    const int lr  = l & 15;
    const int kg  = l >> 4;

    __shared__ short Alds[32][1032];
    __shared__ float gbuf[2][4][16][33];
    __shared__ short Ad[128][40];
    __shared__ short Bd[128][40];

    if (bx >= NB) {
        // ================= decoder role =================
        const int d  = bx - NB;
        const int wm = w2 >> 2;           // 0..1 (64-row half)
        const int wn = w2 & 3;            // 0..3 (32-col quarter)
        int lastmb = -1;
        for (int tile = d; tile < NTILE; tile += NDEC) {
            const int mb = tile / 250, nbt = tile - mb * 250;
            const int m0 = mb * 128, n0 = nbt * 128;
            if (mb != lastmb) {
                if (w2 == 0) poll32s(bar + 32, l, (unsigned)(4 * mb + 5));
                __syncthreads();
                lastmb = mb;
            }
            f4v acc[4][2];
            #pragma unroll
            for (int mi = 0; mi < 4; ++mi)
                #pragma unroll
                for (int ni = 0; ni < 2; ++ni) {
                    acc[mi][ni][0] = 0.f; acc[mi][ni][1] = 0.f;
                    acc[mi][ni][2] = 0.f; acc[mi][ni][3] = 0.f;
                }
            for (int kt = 0; kt < 16; ++kt) {
                {
                    int row = tid >> 2, q = (tid & 3) << 3;
                    *(s8v*)&Ad[row][q] = *(const s8v*)(adec + (size_t)(m0 + row) * 512 + kt * 32 + q);
                    *(s8v*)&Bd[row][q] = *(const s8v*)(dbf  + (size_t)(n0 + row) * 512 + kt * 32 + q);
                }
                __syncthreads();
                s8v af[4], bfr[2];
                #pragma unroll
                for (int i = 0; i < 4; ++i)
                    af[i] = *(const s8v*)&Ad[wm * 64 + i * 16 + lr][kg * 8];
                #pragma unroll
                for (int j = 0; j < 2; ++j)
                    bfr[j] = *(const s8v*)&Bd[wn * 32 + j * 16 + lr][kg * 8];
                #pragma unroll
                for (int mi = 0; mi < 4; ++mi)
                    #pragma unroll
                    for (int ni = 0; ni < 2; ++ni)
                        acc[mi][ni] = mf16(af[mi], bfr[ni], acc[mi][ni]);
                __syncthreads();
            }
            #pragma unroll
            for (int mi = 0; mi < 4; ++mi)
                #pragma unroll
                for (int ni = 0; ni < 2; ++ni) {
                    int n = n0 + wn * 32 + ni * 16 + lr;
                    float bb = db[n];
                    #pragma unroll
                    for (int r = 0; r < 4; ++r) {
                        int m = m0 + wm * 64 + mi * 16 + kg * 4 + r;
                        out[(size_t)m * NVOC + n] = acc[mi][ni][r] + bb;
                    }
                }
        }
        return;
    }

    // ================= recurrence roles =================
    const int bl    = bx;
    const int layer = bl >> 5;
    const int j0    = (bl & 31) * 16;
    const int g     = w2 & 3;
    const int kh    = w2 >> 2;

    // one-time: weight slice fp32 -> hi/lo bf16 fragments in VGPRs
    const int gr = g * 512 + j0 + lr;
    s8v wh[16], wlo[16];
    if (layer == 0) {
        #pragma unroll
        for (int ks = 0; ks < 8; ++ks) {
            const float* src = U0f + (size_t)gr * 512 + kh * 256 + ks * 32 + kg * 8;
            float4 va = *(const float4*)src;
            float4 vb = *(const float4*)(src + 4);
            float vv[8] = {va.x, va.y, va.z, va.w, vb.x, vb.y, vb.z, vb.w};
            s8v hi, lo;
            #pragma unroll
            for (int e = 0; e < 8; ++e) {
                short h = f2bf(vv[e]);
                hi[e] = h; lo[e] = f2bf(vv[e] - bf2f(h));
            }
            wh[ks] = hi; wlo[ks] = lo;
        }
    } else {
        const float* base = kh ? U1f : W1f;
        #pragma unroll
        for (int ks = 0; ks < 16; ++ks) {
            const float* src = base + (size_t)gr * 512 + ks * 32 + kg * 8;
            float4 va = *(const float4*)src;
            float4 vb = *(const float4*)(src + 4);
            float vv[8] = {va.x, va.y, va.z, va.w, vb.x, vb.y, vb.z, vb.w};
            s8v hi, lo;
            #pragma unroll
            for (int e = 0; e < 8; ++e) {
                short h = f2bf(vv[e]);
                hi[e] = h; lo[e] = f2bf(vv[e] - bf2f(h));
            }
            wh[ks] = hi; wlo[ks] = lo;
        }
    }

    const int eb = tid >> 4;
    const int ej = tid & 15;
    const int jj = j0 + ej;
    const float bi = bias[jj];
    const float bf_ = bias[512 + jj];
    const float bg = bias[1024 + jj];
    const float bo = bias[1536 + jj];
    float cst = 0.f;

    short* h0r = hbuf;                        // [8][32][512]
    short* h1r = hbuf + 8 * BAT * HID;        // [2][32][512]

    for (int it = 0; it <= SEQ; ++it) {
        const bool active = (layer == 0) ? (it < SEQ) : (it >= 1);
        const unsigned itu = (unsigned)it;
        const int s0w = it & 7;
        const int s0r = (it + 7) & 7;
        const int s1w = (it + 1) & 1;
        const int s1r = it & 1;

        if (layer == 0) {
            float gx0 = 0.f, gx1 = 0.f, gx2 = 0.f, gx3 = 0.f;
            if (active) {
                const float* gp = Gx + ((size_t)it * BAT + eb) * 2048 + jj;
                gx0 = gp[0]; gx1 = gp[512]; gx2 = gp[1024]; gx3 = gp[1536];
            }
            if (it > 0) {
                if (w2 == 0) pollwait(bar, l, itu, (it >= 7) ? itu - 6u : 0u);
                __syncthreads();
            }
            if (active) {
                const short* s = h0r + s0r * BAT * HID;
                u64 va[8];
                #pragma unroll
                for (int i = 0; i < 8; ++i) {
                    int c = tid + i * 512;
                    va[i] = cohload8(s + (c >> 7) * HID + (c & 127) * 4);
                }
                #pragma unroll
                for (int i = 0; i < 8; ++i) {
                    int c = tid + i * 512;
                    *(u64*)&Alds[c >> 7][(c & 127) * 4] = va[i];
                }
            }
            __syncthreads();
            if (active) {
                f4v a0h, a0l, a1h, a1l;
                a0h[0]=0.f; a0h[1]=0.f; a0h[2]=0.f; a0h[3]=0.f;
                a0l = a0h; a1h = a0h; a1l = a0h;
                #pragma unroll
                for (int ks = 0; ks < 8; ++ks) {
                    const int k = kh * 256 + ks * 32 + kg * 8;
                    s8v a0 = *(const s8v*)&Alds[lr][k];
                    s8v a1 = *(const s8v*)&Alds[16 + lr][k];
                    a0h = mf16(a0, wh[ks],  a0h);
                    a0l = mf16(a0, wlo[ks], a0l);
                    a1h = mf16(a1, wh[ks],  a1h);
                    a1l = mf16(a1, wlo[ks], a1l);
                }
                #pragma unroll
                for (int r = 0; r < 4; ++r) {
                    gbuf[kh][g][lr][kg * 4 + r]      = a0h[r] + a0l[r];
                    gbuf[kh][g][lr][16 + kg * 4 + r] = a1h[r] + a1l[r];
                }
            }
            __syncthreads();
            unsigned short hs = 0;
            if (active) {
                float si = gbuf[0][0][ej][eb] + gbuf[1][0][ej][eb] + gx0;
                float sf = gbuf[0][1][ej][eb] + gbuf[1][1][ej][eb] + gx1;
                float sg = gbuf[0][2][ej][eb] + gbuf[1][2][ej][eb] + gx2;
                float so = gbuf[0][3][ej][eb] + gbuf[1][3][ej][eb] + gx3;
                float gi = sigm(si + bi);
                float gf = sigm(sf + bf_);
                float gg = tanhf(sg + bg);
                float go = sigm(so + bo);
                cst = gf * cst + gi * gg;
                hs = (unsigned short)f2bf(go * tanhf(cst));
                cohstore2(h0r + s0w * BAT * HID + eb * HID + jj, hs);
            }
            if (it < SEQ) {
                asm volatile("s_waitcnt vmcnt(0)" ::: "memory");
                __syncthreads();
                if (tid == 0)
                    __hip_atomic_store(bar + (bl & 31), itu + 1u,
                                       __ATOMIC_RELAXED, __HIP_MEMORY_SCOPE_AGENT);
            }
        } else {
            // ---- layer 1 ----
            if (it > 0) {
                if (w2 == 0) pollwait(bar, l, itu, itu);
                __syncthreads();
            }
            if (active) {
                const short* sA = h0r + s0r * BAT * HID;
                const short* sB = h1r + s1r * BAT * HID;
                u64 va[8], vb[8];
                #pragma unroll
                for (int i = 0; i < 8; ++i) {
                    int c = tid + i * 512;
                    va[i] = cohload8(sA + (c >> 7) * HID + (c & 127) * 4);
                }
                #pragma unroll
                for (int i = 0; i < 8; ++i) {
                    int c = tid + i * 512;
                    vb[i] = cohload8(sB + (c >> 7) * HID + (c & 127) * 4);
                }
                #pragma unroll
                for (int i = 0; i < 8; ++i) {
                    int c = tid + i * 512;
                    *(u64*)&Alds[c >> 7][(c & 127) * 4] = va[i];
                }
                #pragma unroll
                for (int i = 0; i < 8; ++i) {
                    int c = tid + i * 512;
                    *(u64*)&Alds[c >> 7][512 + (c & 127) * 4] = vb[i];
                }
            }
            __syncthreads();
            if (active) {
                f4v a0h, a0l, a1h, a1l;
                a0h[0]=0.f; a0h[1]=0.f; a0h[2]=0.f; a0h[3]=0.f;
                a0l = a0h; a1h = a0h; a1l = a0h;
                #pragma unroll
                for (int ks = 0; ks < 16; ++ks) {
                    const int k = kh * 512 + ks * 32 + kg * 8;
                    s8v a0 = *(const s8v*)&Alds[lr][k];
                    s8v a1 = *(const s8v*)&Alds[16 + lr][k];
                    a0h = mf16(a0, wh[ks],  a0h);
                    a0l = mf16(a0, wlo[ks], a0l);
                    a1h = mf16(a1, wh[ks],  a1h);
                    a1l = mf16(a1, wlo[ks], a1l);
                }
                #pragma unroll
                for (int r = 0; r < 4; ++r) {
                    gbuf[kh][g][lr][kg * 4 + r]      = a0h[r] + a0l[r];
                    gbuf[kh][g][lr][16 + kg * 4 + r] = a1h[r] + a1l[r];
                }
            }
            __syncthreads();
            unsigned short hs = 0;
            if (active) {
                float si = gbuf[0][0][ej][eb] + gbuf[1][0][ej][eb];
                float sf = gbuf[0][1][ej][eb] + gbuf[1][1][ej][eb];
                float sg = gbuf[0][2][ej][eb] + gbuf[1][2][ej][eb];
                float so = gbuf[0][3][ej][eb] + gbuf[1][3][ej][eb];
                float gi = sigm(si + bi);
                float gf = sigm(sf + bf_);
                float gg = tanhf(sg + bg);
                float go = sigm(so + bo);
                cst = gf * cst + gi * gg;
                hs = (unsigned short)f2bf(go * tanhf(cst));
                cohstore2(h1r + s1w * BAT * HID + eb * HID + jj, hs);
                // adec must be globally visible BEFORE the flag publish
                cohstore2(adec + ((size_t)(it - 1) * BAT + eb) * HID + jj, hs);
            }
            // publish every iteration incl. it==SEQ -> flags1 reaches SEQ+1
            asm volatile("s_waitcnt vmcnt(0)" ::: "memory");
            __syncthreads();
            if (tid == 0)
                __hip_atomic_store(bar + 32 + (bl & 31), itu + 1u,
                                   __ATOMIC_RELAXED, __HIP_MEMORY_SCOPE_AGENT);
        }
    }
}

extern "C" void kernel_launch(void* const* d_in, const int* in_sizes, int n_in,
                              void* d_out, int out_size, void* d_ws, size_t ws_size,
                              hipStream_t stream)
{
    const int*   toks = (const int*)d_in[0];
    const float* emb  = (const float*)d_in[1];
    const float* W0   = (const float*)d_in[2];
    const float* W1   = (const float*)d_in[3];
    const float* U0   = (const float*)d_in[4];
    const float* U1   = (const float*)d_in[5];
    const float* bias = (const float*)d_in[6];
    const float* dw   = (const float*)d_in[7];
    const float* db   = (const float*)d_in[8];
    float* out = (float*)d_out;

    char* ws = (char*)d_ws;
    size_t off = 0;
    auto alloc = [&](size_t bytes) -> void* {
        void* p = ws + off;
        off += (bytes + 255) & ~(size_t)255;
        return p;
    };
    short*    dbf  = (short*)alloc((size_t)NVOC * DIM * 2);
    short*    xemb = (short*)alloc((size_t)SEQ * BAT * DIM * 2);
    short*    w0h  = (short*)alloc(2048ull * 512 * 2);
    short*    w0l  = (short*)alloc(2048ull * 512 * 2);
    float*    Gx   = (float*)alloc((size_t)SEQ * BAT * 2048 * 4);
    short*    hbuf = (short*)alloc(10ull * BAT * HID * 2);
    short*    adec = (short*)alloc((size_t)SEQ * BAT * HID * 2);
    unsigned* bar  = (unsigned*)alloc(256);

    prep_dec<<<(NVOC * DIM / 4 + 255) / 256, 256, 0, stream>>>(dw, dbf);
    prep_w0 <<<(2048 * 512 + 255) / 256, 256, 0, stream>>>(W0, w0h, w0l);
    embed_k <<<(SEQ * BAT * DIM / 4 + 255) / 256, 256, 0, stream>>>(toks, emb, xemb);
    init_k  <<<(10 * BAT * HID + 255) / 256, 256, 0, stream>>>(hbuf, bar);

    gx_gemm<<<32 * 16, 256, 0, stream>>>(xemb, w0h, w0l, Gx);

    rnn_k<<<NB + NDEC, 512, 0, stream>>>(W1, U0, U1, bias, Gx, hbuf, adec,
                                         dbf, db, out, bar);
}

// Round 12
// 793.428 us; speedup vs baseline: 2.9695x; 1.0981x over previous
//
#include <hip/hip_runtime.h>
#include <hip/hip_bf16.h>

// ---------------------------------------------------------------------------
// LSTM LM forward on MI355X — round 12.
// Fused persistent kernel (256 blocks x 512 thr): 32 L0 + 32 L1 + 192 decoder.
// NEW vs r11: decoder LDS transposed+padded (2-way banks), decoder polls
// sleep(16), fast tanh via __expf, L1 software-pipelined (W1·h0 computed in
// the prior iteration's tail -> flags1 pacing chain = poll+32KB+32MFMA+epi).
// ---------------------------------------------------------------------------

#define NVOC 32000
#define DIM  512
#define HID  512
#define SEQ  128
#define BAT  32
#define NB   64      // recurrence blocks (32 per layer)
#define NDEC 192     // decoder blocks
#define NTILE (32 * 250)

typedef short s8v __attribute__((ext_vector_type(8)));
typedef short s4v __attribute__((ext_vector_type(4)));
typedef float f4v __attribute__((ext_vector_type(4)));
typedef unsigned long long u64;

__device__ __forceinline__ short f2bf(float f) {
    unsigned u = __builtin_bit_cast(unsigned, f);
    unsigned r = (u + 0x7fffu + ((u >> 16) & 1u)) >> 16;
    return (short)r;
}
__device__ __forceinline__ float bf2f(short s) {
    unsigned u = ((unsigned)(unsigned short)s) << 16;
    return __builtin_bit_cast(float, u);
}
__device__ __forceinline__ float sigm(float x) { return 1.f / (1.f + __expf(-x)); }
__device__ __forceinline__ float ftanh(float x) {
    float e = __expf(2.f * x);
    return 1.f - 2.f / (e + 1.f);
}

__device__ __forceinline__ f4v mf16(s8v a, s8v b, f4v c) {
    return __builtin_amdgcn_mfma_f32_16x16x32_bf16(a, b, c, 0, 0, 0);
}

// coherent (cross-XCD) loads/stores, bypassing L1+L2
__device__ __forceinline__ u64 cohload8(const short* p) {
    return __hip_atomic_load((const u64*)p, __ATOMIC_RELAXED,
                             __HIP_MEMORY_SCOPE_AGENT);
}
__device__ __forceinline__ void cohstore2(short* p, unsigned short v) {
    __hip_atomic_store((unsigned short*)p, v, __ATOMIC_RELAXED,
                       __HIP_MEMORY_SCOPE_AGENT);
}

// combined poll (one wave): lane<32 checks flags0[l]>=tA, lane>=32 flags1[l-32]>=tB
__device__ __forceinline__ void pollwait(const unsigned* bar, int l,
                                         unsigned tA, unsigned tB) {
    const unsigned* fp = bar + l;
    const unsigned tgt = (l < 32) ? tA : tB;
    while (true) {
        unsigned v = __hip_atomic_load(fp, __ATOMIC_RELAXED,
                                       __HIP_MEMORY_SCOPE_AGENT);
        if (__all((int)(v >= tgt))) break;
    }
}
// 32-flag sleep-poll (decoder, long sleep: mb unlocks every ~20us)
__device__ __forceinline__ void poll32s(const unsigned* f, int l, unsigned tgt) {
    const unsigned* p = f + (l & 31);
    while (true) {
        unsigned v = __hip_atomic_load(p, __ATOMIC_RELAXED,
                                       __HIP_MEMORY_SCOPE_AGENT);
        if (__all((int)(v >= tgt))) break;
        __builtin_amdgcn_s_sleep(16);
    }
}

// ---------------- prep kernels ---------------------------------------------
__global__ __launch_bounds__(256) void prep_dec(const float* __restrict__ dw,
                                                short* __restrict__ dbf)
{
    int id = blockIdx.x * 256 + threadIdx.x;
    if (id >= (NVOC * DIM) / 4) return;
    int e = id * 4;
    float4 v = *(const float4*)(dw + e);
    s4v o; o[0] = f2bf(v.x); o[1] = f2bf(v.y); o[2] = f2bf(v.z); o[3] = f2bf(v.w);
    *(s4v*)(dbf + e) = o;
}

__global__ __launch_bounds__(256) void prep_w0(const float* __restrict__ W0,
                                               short* __restrict__ w0h,
                                               short* __restrict__ w0l)
{
    int id = blockIdx.x * 256 + threadIdx.x;
    if (id >= 2048 * 512) return;
    float v = W0[id];
    short h = f2bf(v);
    w0h[id] = h;
    w0l[id] = f2bf(v - bf2f(h));
}

__global__ __launch_bounds__(256) void embed_k(const int* __restrict__ toks,
                                               const float* __restrict__ emb,
                                               short* __restrict__ xemb)
{
    int id = blockIdx.x * 256 + threadIdx.x;
    if (id >= (SEQ * BAT * DIM) / 4) return;
    int e  = id * 4;
    int tb = e >> 9;
    int k4 = e & 511;
    int tok = toks[tb];
    float4 v = *(const float4*)(emb + (size_t)tok * DIM + k4);
    s4v o; o[0] = f2bf(v.x); o[1] = f2bf(v.y); o[2] = f2bf(v.z); o[3] = f2bf(v.w);
    *(s4v*)(xemb + e) = o;
}

__global__ __launch_bounds__(256) void init_k(short* __restrict__ hbuf,
                                              unsigned* __restrict__ bar)
{
    int id = blockIdx.x * 256 + threadIdx.x;
    if (id < 10 * BAT * HID) hbuf[id] = 0;
    if (id < 64) bar[id] = 0;
}

// ---------------- Gx0 GEMM: [4096,2048] = xemb @ (W0hi+W0lo)^T, fp32 out ----
__global__ __launch_bounds__(256) void gx_gemm(
    const short* __restrict__ A,
    const short* __restrict__ Bh,
    const short* __restrict__ Bl,
    float* __restrict__ out)
{
    const int nb = blockIdx.x & 15, mb = blockIdx.x >> 4;
    const int m0 = mb * 128, n0 = nb * 128;
    __shared__ short Alds[128][40];
    __shared__ short Bhl[128][40];
    __shared__ short Bll[128][40];
    const int tid = threadIdx.x, l = tid & 63, w = tid >> 6;
    const int wr = w >> 1, wc = w & 1;
    const int lr = l & 15, kg = l >> 4;

    f4v acc[4][4];
    #pragma unroll
    for (int mi = 0; mi < 4; ++mi)
        #pragma unroll
        for (int ni = 0; ni < 4; ++ni) {
            acc[mi][ni][0] = 0.f; acc[mi][ni][1] = 0.f;
            acc[mi][ni][2] = 0.f; acc[mi][ni][3] = 0.f;
        }

    for (int kt = 0; kt < 16; ++kt) {
        #pragma unroll
        for (int i = 0; i < 2; ++i) {
            int c = tid + i * 256;
            int row = c >> 2, q = (c & 3) << 3;
            *(s8v*)&Alds[row][q] = *(const s8v*)(A  + (size_t)(m0 + row) * 512 + kt * 32 + q);
            *(s8v*)&Bhl[row][q]  = *(const s8v*)(Bh + (size_t)(n0 + row) * 512 + kt * 32 + q);
            *(s8v*)&Bll[row][q]  = *(const s8v*)(Bl + (size_t)(n0 + row) * 512 + kt * 32 + q);
        }
        __syncthreads();
        s8v af[4], bhf[4], blf[4];
        #pragma unroll
        for (int i = 0; i < 4; ++i) {
            af[i]  = *(const s8v*)&Alds[wr * 64 + i * 16 + lr][kg * 8];
            bhf[i] = *(const s8v*)&Bhl[wc * 64 + i * 16 + lr][kg * 8];
            blf[i] = *(const s8v*)&Bll[wc * 64 + i * 16 + lr][kg * 8];
        }
        #pragma unroll
        for (int mi = 0; mi < 4; ++mi)
            #pragma unroll
            for (int ni = 0; ni < 4; ++ni) {
                acc[mi][ni] = mf16(af[mi], bhf[ni], acc[mi][ni]);
                acc[mi][ni] = mf16(af[mi], blf[ni], acc[mi][ni]);
            }
        __syncthreads();
    }

    #pragma unroll
    for (int mi = 0; mi < 4; ++mi)
        #pragma unroll
        for (int ni = 0; ni < 4; ++ni) {
            int n = n0 + wc * 64 + ni * 16 + lr;
            #pragma unroll
            for (int r = 0; r < 4; ++r) {
                int m = m0 + wr * 64 + mi * 16 + kg * 4 + r;
                out[(size_t)m * 2048 + n] = acc[mi][ni][r];
            }
        }
}

// ---------------- fused persistent recurrence + decoder ---------------------
__global__ __launch_bounds__(512, 1) void rnn_k(
    const float* __restrict__ W1f, const float* __restrict__ U0f,
    const float* __restrict__ U1f,
    const float* __restrict__ bias,
    const float* __restrict__ Gx,   // [4096][2048] fp32
    short* __restrict__ hbuf,       // h0[8][32][512] then h1[2][32][512]
    short* __restrict__ adec,       // [4096][512] bf16 (write-through)
    const short* __restrict__ dbf,  // dec_w bf16 [32000][512]
    const float* __restrict__ db,   // dec bias [32000]
    float* __restrict__ out,        // [4096][32000]
    unsigned* __restrict__ bar)     // flags0[0..31], flags1[32..63]
{
    const int tid = threadIdx.x;
    const int bx  = blockIdx.x;
    const int w2  = tid >> 6;
    const int l   = tid & 63;
    const int lr  = l & 15;
    const int kg  = l >> 4;

    __shared__ short Alds[32][520];
    __shared__ float gbuf[2][4][16][33];
    __shared__ float pbuf[2][4][16][33];
    __shared__ s8v AdT[4][132];      // transposed+padded: 2-way banks
    __shared__ s8v BdT[4][132];

    if (bx >= NB) {
        // ================= decoder role =================
        const int d  = bx - NB;
        const int wm = w2 >> 2;           // 0..1 (64-row half)
        const int wn = w2 & 3;            // 0..3 (32-col quarter)
        const int drow = tid >> 2, dq = tid & 3;
        int lastmb = -1;
        for (int tile = d; tile < NTILE; tile += NDEC) {
            const int mb = tile / 250, nbt = tile - mb * 250;
            const int m0 = mb * 128, n0 = nbt * 128;
            if (mb != lastmb) {
                if (w2 == 0) poll32s(bar + 32, l, (unsigned)(4 * mb + 5));
                __syncthreads();
                lastmb = mb;
            }
            f4v acc[4][2];
            #pragma unroll
            for (int mi = 0; mi < 4; ++mi)
                #pragma unroll
                for (int ni = 0; ni < 2; ++ni) {
                    acc[mi][ni][0] = 0.f; acc[mi][ni][1] = 0.f;
                    acc[mi][ni][2] = 0.f; acc[mi][ni][3] = 0.f;
                }
            for (int kt = 0; kt < 16; ++kt) {
                AdT[dq][drow] = *(const s8v*)(adec + (size_t)(m0 + drow) * 512 + kt * 32 + dq * 8);
                BdT[dq][drow] = *(const s8v*)(dbf  + (size_t)(n0 + drow) * 512 + kt * 32 + dq * 8);
                __syncthreads();
                s8v af[4], bfr[2];
                #pragma unroll
                for (int i = 0; i < 4; ++i)
                    af[i] = AdT[kg][wm * 64 + i * 16 + lr];
                #pragma unroll
                for (int j = 0; j < 2; ++j)
                    bfr[j] = BdT[kg][wn * 32 + j * 16 + lr];
                #pragma unroll
                for (int mi = 0; mi < 4; ++mi)
                    #pragma unroll
                    for (int ni = 0; ni < 2; ++ni)
                        acc[mi][ni] = mf16(af[mi], bfr[ni], acc[mi][ni]);
                __syncthreads();
            }
            #pragma unroll
            for (int mi = 0; mi < 4; ++mi)
                #pragma unroll
                for (int ni = 0; ni < 2; ++ni) {
                    int n = n0 + wn * 32 + ni * 16 + lr;
                    float bb = db[n];
                    #pragma unroll
                    for (int r = 0; r < 4; ++r) {
                        int m = m0 + wm * 64 + mi * 16 + kg * 4 + r;
                        out[(size_t)m * NVOC + n] = acc[mi][ni][r] + bb;
                    }
                }
        }
        return;
    }

    // ================= recurrence roles =================
    const int bl    = bx;
    const int layer = bl >> 5;
    const int j0    = (bl & 31) * 16;
    const int g     = w2 & 3;
    const int kh    = w2 >> 2;

    const int eb = tid >> 4;
    const int ej = tid & 15;
    const int jj = j0 + ej;
    const float bi = bias[jj];
    const float bf_ = bias[512 + jj];
    const float bg = bias[1024 + jj];
    const float bo = bias[1536 + jj];
    float cst = 0.f;

    short* h0r = hbuf;                        // [8][32][512]
    short* h1r = hbuf + 8 * BAT * HID;        // [2][32][512]

    // stage 32x512 bf16 coherent buffer -> Alds cols 0..511
    auto stageK512 = [&](const short* s) {
        u64 va[8];
        #pragma unroll
        for (int i = 0; i < 8; ++i) {
            int c = tid + i * 512;
            va[i] = cohload8(s + (c >> 7) * HID + (c & 127) * 4);
        }
        #pragma unroll
        for (int i = 0; i < 8; ++i) {
            int c = tid + i * 512;
            *(u64*)&Alds[c >> 7][(c & 127) * 4] = va[i];
        }
    };
    // 8-ks hi/lo MFMA on this wave's K-half; partials -> dst
    auto mfma8 = [&](const s8v* WH, const s8v* WL, float (&dst)[2][4][16][33]) {
        f4v a0h = {0.f, 0.f, 0.f, 0.f};
        f4v a0l = a0h, a1h = a0h, a1l = a0h;
        #pragma unroll
        for (int ks = 0; ks < 8; ++ks) {
            const int k = kh * 256 + ks * 32 + kg * 8;
            s8v a0 = *(const s8v*)&Alds[lr][k];
            s8v a1 = *(const s8v*)&Alds[16 + lr][k];
            a0h = mf16(a0, WH[ks], a0h);
            a0l = mf16(a0, WL[ks], a0l);
            a1h = mf16(a1, WH[ks], a1h);
            a1l = mf16(a1, WL[ks], a1l);
        }
        #pragma unroll
        for (int r = 0; r < 4; ++r) {
            dst[kh][g][lr][kg * 4 + r]      = a0h[r] + a0l[r];
            dst[kh][g][lr][16 + kg * 4 + r] = a1h[r] + a1l[r];
        }
    };
    // fp32 -> hi/lo bf16 fragment loader (8 ks at this wave's K-half)
    const int gr = g * 512 + j0 + lr;
    auto loadw = [&](const float* M, s8v* WH, s8v* WL) {
        #pragma unroll
        for (int ks = 0; ks < 8; ++ks) {
            const float* src = M + (size_t)gr * 512 + kh * 256 + ks * 32 + kg * 8;
            float4 va = *(const float4*)src;
            float4 vb = *(const float4*)(src + 4);
            float vv[8] = {va.x, va.y, va.z, va.w, vb.x, vb.y, vb.z, vb.w};
            s8v hi, lo;
            #pragma unroll
            for (int e = 0; e < 8; ++e) {
                short h = f2bf(vv[e]);
                hi[e] = h; lo[e] = f2bf(vv[e] - bf2f(h));
            }
            WH[ks] = hi; WL[ks] = lo;
        }
    };

    if (layer == 0) {
        // ---------------- L0: h0(t) = act(U0·h0(t-1) + Gx(t)) ----------------
        s8v wh[8], wl[8];
        loadw(U0f, wh, wl);
        for (int it = 0; it < SEQ; ++it) {
            const unsigned itu = (unsigned)it;
            const float* gp = Gx + ((size_t)it * BAT + eb) * 2048 + jj;
            float gx0 = gp[0], gx1 = gp[512], gx2 = gp[1024], gx3 = gp[1536];
            if (it > 0) {
                if (w2 == 0) pollwait(bar, l, itu, (it >= 7) ? itu - 6u : 0u);
                __syncthreads();
            }
            stageK512(h0r + ((it + 7) & 7) * (BAT * HID));
            __syncthreads();
            mfma8(wh, wl, gbuf);
            __syncthreads();
            float si = gbuf[0][0][ej][eb] + gbuf[1][0][ej][eb] + gx0;
            float sf = gbuf[0][1][ej][eb] + gbuf[1][1][ej][eb] + gx1;
            float sg = gbuf[0][2][ej][eb] + gbuf[1][2][ej][eb] + gx2;
            float so = gbuf[0][3][ej][eb] + gbuf[1][3][ej][eb] + gx3;
            float gi = sigm(si + bi);
            float gf = sigm(sf + bf_);
            float gg = ftanh(sg + bg);
            float go = sigm(so + bo);
            cst = gf * cst + gi * gg;
            unsigned short hs = (unsigned short)f2bf(go * ftanh(cst));
            cohstore2(h0r + (it & 7) * (BAT * HID) + eb * HID + jj, hs);
            asm volatile("s_waitcnt vmcnt(0)" ::: "memory");
            __syncthreads();
            if (tid == 0)
                __hip_atomic_store(bar + (bl & 31), itu + 1u,
                                   __ATOMIC_RELAXED, __HIP_MEMORY_SCOPE_AGENT);
        }
    } else {
        // -------- L1 (pipelined): h1(t) = act(U1·h1(t-1) + pbuf:W1·h0(t)) ----
        s8v whU[8], wlU[8], whW[8], wlW[8];
        loadw(U1f, whU, wlU);
        loadw(W1f, whW, wlW);
        // prologue: pbuf = W1·h0(0)
        if (w2 == 0) pollwait(bar, l, 1u, 0u);
        __syncthreads();
        stageK512(h0r);                        // slot 0 = h0(0)
        __syncthreads();
        mfma8(whW, wlW, pbuf);
        for (int it = 1; it <= SEQ; ++it) {
            const unsigned itu = (unsigned)it;
            // pacing phase: compute h1(it-1)
            if (w2 == 0) pollwait(bar, l, 0u, (it >= 2) ? itu : 0u);
            __syncthreads();                   // also orders pbuf/tail writes
            stageK512(h1r + (it & 1) * (BAT * HID));   // h1(it-2)
            __syncthreads();
            mfma8(whU, wlU, gbuf);
            __syncthreads();
            float si = gbuf[0][0][ej][eb] + gbuf[1][0][ej][eb]
                     + pbuf[0][0][ej][eb] + pbuf[1][0][ej][eb];
            float sf = gbuf[0][1][ej][eb] + gbuf[1][1][ej][eb]
                     + pbuf[0][1][ej][eb] + pbuf[1][1][ej][eb];
            float sg = gbuf[0][2][ej][eb] + gbuf[1][2][ej][eb]
                     + pbuf[0][2][ej][eb] + pbuf[1][2][ej][eb];
            float so = gbuf[0][3][ej][eb] + gbuf[1][3][ej][eb]
                     + pbuf[0][3][ej][eb] + pbuf[1][3][ej][eb];
            float gi = sigm(si + bi);
            float gf = sigm(sf + bf_);
            float gg = ftanh(sg + bg);
            float go = sigm(so + bo);
            cst = gf * cst + gi * gg;
            unsigned short hs = (unsigned short)f2bf(go * ftanh(cst));
            cohstore2(h1r + ((it + 1) & 1) * (BAT * HID) + eb * HID + jj, hs);
            cohstore2(adec + ((size_t)(it - 1) * BAT + eb) * HID + jj, hs);
            asm volatile("s_waitcnt vmcnt(0)" ::: "memory");
            __syncthreads();
            if (tid == 0)
                __hip_atomic_store(bar + 32 + (bl & 31), itu + 1u,
                                   __ATOMIC_RELAXED, __HIP_MEMORY_SCOPE_AGENT);
            // tail phase (off pacing chain): pbuf = W1·h0(it) for next iter
            if (it < SEQ) {
                if (w2 == 0) pollwait(bar, l, itu + 1u, 0u);
                __syncthreads();
                stageK512(h0r + (it & 7) * (BAT * HID));
                __syncthreads();
                mfma8(whW, wlW, pbuf);
            }
        }
    }
}

extern "C" void kernel_launch(void* const* d_in, const int* in_sizes, int n_in,
                              void* d_out, int out_size, void* d_ws, size_t ws_size,
                              hipStream_t stream)
{
    const int*   toks = (const int*)d_in[0];
    const float* emb  = (const float*)d_in[1];
    const float* W0   = (const float*)d_in[2];
    const float* W1   = (const float*)d_in[3];
    const float* U0   = (const float*)d_in[4];
    const float* U1   = (const float*)d_in[5];
    const float* bias = (const float*)d_in[6];
    const float* dw   = (const float*)d_in[7];
    const float* db   = (const float*)d_in[8];
    float* out = (float*)d_out;

    char* ws = (char*)d_ws;
    size_t off = 0;
    auto alloc = [&](size_t bytes) -> void* {
        void* p = ws + off;
        off += (bytes + 255) & ~(size_t)255;
        return p;
    };
    short*    dbf  = (short*)alloc((size_t)NVOC * DIM * 2);
    short*    xemb = (short*)alloc((size_t)SEQ * BAT * DIM * 2);
    short*    w0h  = (short*)alloc(2048ull * 512 * 2);
    short*    w0l  = (short*)alloc(2048ull * 512 * 2);
    float*    Gx   = (float*)alloc((size_t)SEQ * BAT * 2048 * 4);
    short*    hbuf = (short*)alloc(10ull * BAT * HID * 2);
    short*    adec = (short*)alloc((size_t)SEQ * BAT * HID * 2);
    unsigned* bar  = (unsigned*)alloc(256);

    prep_dec<<<(NVOC * DIM / 4 + 255) / 256, 256, 0, stream>>>(dw, dbf);
    prep_w0 <<<(2048 * 512 + 255) / 256, 256, 0, stream>>>(W0, w0h, w0l);
    embed_k <<<(SEQ * BAT * DIM / 4 + 255) / 256, 256, 0, stream>>>(toks, emb, xemb);
    init_k  <<<(10 * BAT * HID + 255) / 256, 256, 0, stream>>>(hbuf, bar);

    gx_gemm<<<32 * 16, 256, 0, stream>>>(xemb, w0h, w0l, Gx);

    rnn_k<<<NB + NDEC, 512, 0, stream>>>(W1, U0, U1, bias, Gx, hbuf, adec,
                                         dbf, db, out, bar);
}

// Round 13
// 699.041 us; speedup vs baseline: 3.3705x; 1.1350x over previous
//
#include <hip/hip_runtime.h>
#include <hip/hip_bf16.h>

// ---------------------------------------------------------------------------
// LSTM LM forward on MI355X — round 13.
// Fused persistent kernel (256 blocks x 512 thr): 32 L0 + 32 L1 + 192 decoder.
// NEW vs r12: sentinel-polled write-once rings (129 slots) for h0/h1 — the
// data stores ARE the readiness signal (bf16 0xFFFF NaN sentinel, impossible
// as tanh output). No flags on the h-chain; flags1 kept only for decoder
// mb-gating, published every 4th step.
// ---------------------------------------------------------------------------

#define NVOC 32000
#define DIM  512
#define HID  512
#define SEQ  128
#define BAT  32
#define NB   64      // recurrence blocks (32 per layer)
#define NDEC 192     // decoder blocks
#define NTILE (32 * 250)
#define SLOT (BAT * HID)           // 16384 shorts per ring slot

typedef short s8v __attribute__((ext_vector_type(8)));
typedef short s4v __attribute__((ext_vector_type(4)));
typedef float f4v __attribute__((ext_vector_type(4)));
typedef unsigned long long u64;

__device__ __forceinline__ short f2bf(float f) {
    unsigned u = __builtin_bit_cast(unsigned, f);
    unsigned r = (u + 0x7fffu + ((u >> 16) & 1u)) >> 16;
    return (short)r;
}
__device__ __forceinline__ float bf2f(short s) {
    unsigned u = ((unsigned)(unsigned short)s) << 16;
    return __builtin_bit_cast(float, u);
}
__device__ __forceinline__ float sigm(float x) { return 1.f / (1.f + __expf(-x)); }
__device__ __forceinline__ float ftanh(float x) {
    float e = __expf(2.f * x);
    return 1.f - 2.f / (e + 1.f);
}

__device__ __forceinline__ f4v mf16(s8v a, s8v b, f4v c) {
    return __builtin_amdgcn_mfma_f32_16x16x32_bf16(a, b, c, 0, 0, 0);
}

// coherent (cross-XCD) loads/stores, bypassing L1+L2
__device__ __forceinline__ u64 cohload8(const short* p) {
    return __hip_atomic_load((const u64*)p, __ATOMIC_RELAXED,
                             __HIP_MEMORY_SCOPE_AGENT);
}
__device__ __forceinline__ void cohstore2(short* p, unsigned short v) {
    __hip_atomic_store((unsigned short*)p, v, __ATOMIC_RELAXED,
                       __HIP_MEMORY_SCOPE_AGENT);
}

// any halfword == 0xFFFF ?  (has-zero-halfword test on ~v)
__device__ __forceinline__ bool hasSent(u64 v) {
    u64 n = ~v;
    return ((n - 0x0001000100010001ull) & ~n & 0x8000800080008000ull) != 0ull;
}

// 32-flag sleep-poll (decoder only)
__device__ __forceinline__ void poll32s(const unsigned* f, int l, unsigned tgt) {
    const unsigned* p = f + (l & 31);
    while (true) {
        unsigned v = __hip_atomic_load(p, __ATOMIC_RELAXED,
                                       __HIP_MEMORY_SCOPE_AGENT);
        if (__all((int)(v >= tgt))) break;
        __builtin_amdgcn_s_sleep(16);
    }
}

// ---------------- prep kernels ---------------------------------------------
__global__ __launch_bounds__(256) void prep_dec(const float* __restrict__ dw,
                                                short* __restrict__ dbf)
{
    int id = blockIdx.x * 256 + threadIdx.x;
    if (id >= (NVOC * DIM) / 4) return;
    int e = id * 4;
    float4 v = *(const float4*)(dw + e);
    s4v o; o[0] = f2bf(v.x); o[1] = f2bf(v.y); o[2] = f2bf(v.z); o[3] = f2bf(v.w);
    *(s4v*)(dbf + e) = o;
}

__global__ __launch_bounds__(256) void prep_w0(const float* __restrict__ W0,
                                               short* __restrict__ w0h,
                                               short* __restrict__ w0l)
{
    int id = blockIdx.x * 256 + threadIdx.x;
    if (id >= 2048 * 512) return;
    float v = W0[id];
    short h = f2bf(v);
    w0h[id] = h;
    w0l[id] = f2bf(v - bf2f(h));
}

__global__ __launch_bounds__(256) void embed_k(const int* __restrict__ toks,
                                               const float* __restrict__ emb,
                                               short* __restrict__ xemb)
{
    int id = blockIdx.x * 256 + threadIdx.x;
    if (id >= (SEQ * BAT * DIM) / 4) return;
    int e  = id * 4;
    int tb = e >> 9;
    int k4 = e & 511;
    int tok = toks[tb];
    float4 v = *(const float4*)(emb + (size_t)tok * DIM + k4);
    s4v o; o[0] = f2bf(v.x); o[1] = f2bf(v.y); o[2] = f2bf(v.z); o[3] = f2bf(v.w);
    *(s4v*)(xemb + e) = o;
}

// rings: ring0[129][SLOT] then ring1[129][SLOT]. slot0 = zeros (h(-1)),
// slots 1..128 = 0xFFFF sentinel. + zero flags.
__global__ __launch_bounds__(256) void init_k(short* __restrict__ hbuf,
                                              unsigned* __restrict__ bar)
{
    int id = blockIdx.x * 256 + threadIdx.x;   // u64 index
    const int ringU64 = 129 * SLOT / 4;        // u64 per ring
    if (id < 2 * ringU64) {
        int r = id % ringU64;                  // position within ring
        u64 v = (r < SLOT / 4) ? 0ull : 0xFFFFFFFFFFFFFFFFull;
        ((u64*)hbuf)[id] = v;
    }
    if (id < 64) bar[id] = 0;
}

// ---------------- Gx0 GEMM: [4096,2048] = xemb @ (W0hi+W0lo)^T, fp32 out ----
__global__ __launch_bounds__(256) void gx_gemm(
    const short* __restrict__ A,
    const short* __restrict__ Bh,
    const short* __restrict__ Bl,
    float* __restrict__ out)
{
    const int nb = blockIdx.x & 15, mb = blockIdx.x >> 4;
    const int m0 = mb * 128, n0 = nb * 128;
    __shared__ short Alds[128][40];
    __shared__ short Bhl[128][40];
    __shared__ short Bll[128][40];
    const int tid = threadIdx.x, l = tid & 63, w = tid >> 6;
    const int wr = w >> 1, wc = w & 1;
    const int lr = l & 15, kg = l >> 4;

    f4v acc[4][4];
    #pragma unroll
    for (int mi = 0; mi < 4; ++mi)
        #pragma unroll
        for (int ni = 0; ni < 4; ++ni) {
            acc[mi][ni][0] = 0.f; acc[mi][ni][1] = 0.f;
            acc[mi][ni][2] = 0.f; acc[mi][ni][3] = 0.f;
        }

    for (int kt = 0; kt < 16; ++kt) {
        #pragma unroll
        for (int i = 0; i < 2; ++i) {
            int c = tid + i * 256;
            int row = c >> 2, q = (c & 3) << 3;
            *(s8v*)&Alds[row][q] = *(const s8v*)(A  + (size_t)(m0 + row) * 512 + kt * 32 + q);
            *(s8v*)&Bhl[row][q]  = *(const s8v*)(Bh + (size_t)(n0 + row) * 512 + kt * 32 + q);
            *(s8v*)&Bll[row][q]  = *(const s8v*)(Bl + (size_t)(n0 + row) * 512 + kt * 32 + q);
        }
        __syncthreads();
        s8v af[4], bhf[4], blf[4];
        #pragma unroll
        for (int i = 0; i < 4; ++i) {
            af[i]  = *(const s8v*)&Alds[wr * 64 + i * 16 + lr][kg * 8];
            bhf[i] = *(const s8v*)&Bhl[wc * 64 + i * 16 + lr][kg * 8];
            blf[i] = *(const s8v*)&Bll[wc * 64 + i * 16 + lr][kg * 8];
        }
        #pragma unroll
        for (int mi = 0; mi < 4; ++mi)
            #pragma unroll
            for (int ni = 0; ni < 4; ++ni) {
                acc[mi][ni] = mf16(af[mi], bhf[ni], acc[mi][ni]);
                acc[mi][ni] = mf16(af[mi], blf[ni], acc[mi][ni]);
            }
        __syncthreads();
    }

    #pragma unroll
    for (int mi = 0; mi < 4; ++mi)
        #pragma unroll
        for (int ni = 0; ni < 4; ++ni) {
            int n = n0 + wc * 64 + ni * 16 + lr;
            #pragma unroll
            for (int r = 0; r < 4; ++r) {
                int m = m0 + wr * 64 + mi * 16 + kg * 4 + r;
                out[(size_t)m * 2048 + n] = acc[mi][ni][r];
            }
        }
}

// ---------------- fused persistent recurrence + decoder ---------------------
__global__ __launch_bounds__(512, 1) void rnn_k(
    const float* __restrict__ W1f, const float* __restrict__ U0f,
    const float* __restrict__ U1f,
    const float* __restrict__ bias,
    const float* __restrict__ Gx,   // [4096][2048] fp32
    short* __restrict__ hbuf,       // ring0[129][SLOT] then ring1[129][SLOT]
    short* __restrict__ adec,       // [4096][512] bf16 (write-through)
    const short* __restrict__ dbf,  // dec_w bf16 [32000][512]
    const float* __restrict__ db,   // dec bias [32000]
    float* __restrict__ out,        // [4096][32000]
    unsigned* __restrict__ bar)     // flags1[32..63] (decoder gating only)
{
    const int tid = threadIdx.x;
    const int bx  = blockIdx.x;
    const int w2  = tid >> 6;
    const int l   = tid & 63;
    const int lr  = l & 15;
    const int kg  = l >> 4;

    __shared__ short Alds[32][520];
    __shared__ float gbuf[2][4][16][33];
    __shared__ float pbuf[2][4][16][33];
    __shared__ s8v AdT[4][132];
    __shared__ s8v BdT[4][132];

    if (bx >= NB) {
        // ================= decoder role =================
        const int d  = bx - NB;
        const int wm = w2 >> 2;
        const int wn = w2 & 3;
        const int drow = tid >> 2, dq = tid & 3;
        int lastmb = -1;
        for (int tile = d; tile < NTILE; tile += NDEC) {
            const int mb = tile / 250, nbt = tile - mb * 250;
            const int m0 = mb * 128, n0 = nbt * 128;
            if (mb != lastmb) {
                if (w2 == 0) poll32s(bar + 32, l, (unsigned)(4 * mb + 5));
                __syncthreads();
                lastmb = mb;
            }
            f4v acc[4][2];
            #pragma unroll
            for (int mi = 0; mi < 4; ++mi)
                #pragma unroll
                for (int ni = 0; ni < 2; ++ni) {
                    acc[mi][ni][0] = 0.f; acc[mi][ni][1] = 0.f;
                    acc[mi][ni][2] = 0.f; acc[mi][ni][3] = 0.f;
                }
            for (int kt = 0; kt < 16; ++kt) {
                AdT[dq][drow] = *(const s8v*)(adec + (size_t)(m0 + drow) * 512 + kt * 32 + dq * 8);
                BdT[dq][drow] = *(const s8v*)(dbf  + (size_t)(n0 + drow) * 512 + kt * 32 + dq * 8);
                __syncthreads();
                s8v af[4], bfr[2];
                #pragma unroll
                for (int i = 0; i < 4; ++i)
                    af[i] = AdT[kg][wm * 64 + i * 16 + lr];
                #pragma unroll
                for (int j = 0; j < 2; ++j)
                    bfr[j] = BdT[kg][wn * 32 + j * 16 + lr];
                #pragma unroll
                for (int mi = 0; mi < 4; ++mi)
                    #pragma unroll
                    for (int ni = 0; ni < 2; ++ni)
                        acc[mi][ni] = mf16(af[mi], bfr[ni], acc[mi][ni]);
                __syncthreads();
            }
            #pragma unroll
            for (int mi = 0; mi < 4; ++mi)
                #pragma unroll
                for (int ni = 0; ni < 2; ++ni) {
                    int n = n0 + wn * 32 + ni * 16 + lr;
                    float bb = db[n];
                    #pragma unroll
                    for (int r = 0; r < 4; ++r) {
                        int m = m0 + wm * 64 + mi * 16 + kg * 4 + r;
                        out[(size_t)m * NVOC + n] = acc[mi][ni][r] + bb;
                    }
                }
        }
        return;
    }

    // ================= recurrence roles =================
    const int bl    = bx;
    const int layer = bl >> 5;
    const int j0    = (bl & 31) * 16;
    const int g     = w2 & 3;
    const int kh    = w2 >> 2;

    const int eb = tid >> 4;
    const int ej = tid & 15;
    const int jj = j0 + ej;
    const float bi = bias[jj];
    const float bf_ = bias[512 + jj];
    const float bg = bias[1024 + jj];
    const float bo = bias[1536 + jj];
    float cst = 0.f;

    short* ring0 = hbuf;                      // [129][SLOT]: slot t+1 = h0(t)
    short* ring1 = hbuf + 129 * SLOT;         // [129][SLOT]: slot t+1 = h1(t)

    // sentinel-polled stage: 32x512 bf16 slot -> Alds cols 0..511
    auto stageS = [&](const short* s) {
        u64 va[8];
        #pragma unroll
        for (int i = 0; i < 8; ++i) {
            int c = tid + i * 512;
            va[i] = cohload8(s + (c >> 7) * HID + (c & 127) * 4);
        }
        #pragma unroll
        for (int i = 0; i < 8; ++i) {
            int c = tid + i * 512;
            while (hasSent(va[i]))
                va[i] = cohload8(s + (c >> 7) * HID + (c & 127) * 4);
            *(u64*)&Alds[c >> 7][(c & 127) * 4] = va[i];
        }
    };
    auto mfma8 = [&](const s8v* WH, const s8v* WL, float (&dst)[2][4][16][33]) {
        f4v a0h = {0.f, 0.f, 0.f, 0.f};
        f4v a0l = a0h, a1h = a0h, a1l = a0h;
        #pragma unroll
        for (int ks = 0; ks < 8; ++ks) {
            const int k = kh * 256 + ks * 32 + kg * 8;
            s8v a0 = *(const s8v*)&Alds[lr][k];
            s8v a1 = *(const s8v*)&Alds[16 + lr][k];
            a0h = mf16(a0, WH[ks], a0h);
            a0l = mf16(a0, WL[ks], a0l);
            a1h = mf16(a1, WH[ks], a1h);
            a1l = mf16(a1, WL[ks], a1l);
        }
        #pragma unroll
        for (int r = 0; r < 4; ++r) {
            dst[kh][g][lr][kg * 4 + r]      = a0h[r] + a0l[r];
            dst[kh][g][lr][16 + kg * 4 + r] = a1h[r] + a1l[r];
        }
    };
    const int gr = g * 512 + j0 + lr;
    auto loadw = [&](const float* M, s8v* WH, s8v* WL) {
        #pragma unroll
        for (int ks = 0; ks < 8; ++ks) {
            const float* src = M + (size_t)gr * 512 + kh * 256 + ks * 32 + kg * 8;
            float4 va = *(const float4*)src;
            float4 vb = *(const float4*)(src + 4);
            float vv[8] = {va.x, va.y, va.z, va.w, vb.x, vb.y, vb.z, vb.w};
            s8v hi, lo;
            #pragma unroll
            for (int e = 0; e < 8; ++e) {
                short h = f2bf(vv[e]);
                hi[e] = h; lo[e] = f2bf(vv[e] - bf2f(h));
            }
            WH[ks] = hi; WL[ks] = lo;
        }
    };

    if (layer == 0) {
        // ------- L0: h0(t) = act(U0·h0(t-1) + Gx(t)); no flags at all -------
        s8v wh[8], wl[8];
        loadw(U0f, wh, wl);
        for (int it = 0; it < SEQ; ++it) {
            const float* gp = Gx + ((size_t)it * BAT + eb) * 2048 + jj;
            float gx0 = gp[0], gx1 = gp[512], gx2 = gp[1024], gx3 = gp[1536];
            stageS(ring0 + (size_t)it * SLOT);         // h0(it-1)
            __syncthreads();
            mfma8(wh, wl, gbuf);
            __syncthreads();
            float si = gbuf[0][0][ej][eb] + gbuf[1][0][ej][eb] + gx0;
            float sf = gbuf[0][1][ej][eb] + gbuf[1][1][ej][eb] + gx1;
            float sg = gbuf[0][2][ej][eb] + gbuf[1][2][ej][eb] + gx2;
            float so = gbuf[0][3][ej][eb] + gbuf[1][3][ej][eb] + gx3;
            float gi = sigm(si + bi);
            float gf = sigm(sf + bf_);
            float gg = ftanh(sg + bg);
            float go = sigm(so + bo);
            cst = gf * cst + gi * gg;
            unsigned short hs = (unsigned short)f2bf(go * ftanh(cst));
            cohstore2(ring0 + (size_t)(it + 1) * SLOT + eb * HID + jj, hs);
        }
    } else {
        // -- L1 (pipelined): h1(t) = act(U1·h1(t-1) + pbuf:W1·h0(t)) ---------
        s8v whU[8], wlU[8], whW[8], wlW[8];
        loadw(U1f, whU, wlU);
        loadw(W1f, whW, wlW);
        // prologue: pbuf = W1·h0(0)
        stageS(ring0 + 1 * SLOT);
        __syncthreads();
        mfma8(whW, wlW, pbuf);
        for (int it = 1; it <= SEQ; ++it) {
            // pacing: compute h1(it-1) = act(U1·h1(it-2) + pbuf)
            stageS(ring1 + (size_t)(it - 1) * SLOT);   // h1(it-2)
            __syncthreads();
            mfma8(whU, wlU, gbuf);
            __syncthreads();
            float si = gbuf[0][0][ej][eb] + gbuf[1][0][ej][eb]
                     + pbuf[0][0][ej][eb] + pbuf[1][0][ej][eb];
            float sf = gbuf[0][1][ej][eb] + gbuf[1][1][ej][eb]
                     + pbuf[0][1][ej][eb] + pbuf[1][1][ej][eb];
            float sg = gbuf[0][2][ej][eb] + gbuf[1][2][ej][eb]
                     + pbuf[0][2][ej][eb] + pbuf[1][2][ej][eb];
            float so = gbuf[0][3][ej][eb] + gbuf[1][3][ej][eb]
                     + pbuf[0][3][ej][eb] + pbuf[1][3][ej][eb];
            float gi = sigm(si + bi);
            float gf = sigm(sf + bf_);
            float gg = ftanh(sg + bg);
            float go = sigm(so + bo);
            cst = gf * cst + gi * gg;
            unsigned short hs = (unsigned short)f2bf(go * ftanh(cst));
            cohstore2(ring1 + (size_t)it * SLOT + eb * HID + jj, hs);
            cohstore2(adec + ((size_t)(it - 1) * BAT + eb) * HID + jj, hs);
            // decoder gating flag, every 4th step (off the h-chain)
            if ((it & 3) == 0 || it == SEQ) {
                asm volatile("s_waitcnt vmcnt(0)" ::: "memory");
                __syncthreads();
                if (tid == 0)
                    __hip_atomic_store(bar + 32 + (bl & 31), (unsigned)(it + 1),
                                       __ATOMIC_RELAXED, __HIP_MEMORY_SCOPE_AGENT);
            }
            // tail (slack): pbuf = W1·h0(it) for next iteration
            if (it < SEQ) {
                stageS(ring0 + (size_t)(it + 1) * SLOT);   // h0(it)
                __syncthreads();
                mfma8(whW, wlW, pbuf);
            }
        }
    }
}

extern "C" void kernel_launch(void* const* d_in, const int* in_sizes, int n_in,
                              void* d_out, int out_size, void* d_ws, size_t ws_size,
                              hipStream_t stream)
{
    const int*   toks = (const int*)d_in[0];
    const float* emb  = (const float*)d_in[1];
    const float* W0   = (const float*)d_in[2];
    const float* W1   = (const float*)d_in[3];
    const float* U0   = (const float*)d_in[4];
    const float* U1   = (const float*)d_in[5];
    const float* bias = (const float*)d_in[6];
    const float* dw   = (const float*)d_in[7];
    const float* db   = (const float*)d_in[8];
    float* out = (float*)d_out;

    char* ws = (char*)d_ws;
    size_t off = 0;
    auto alloc = [&](size_t bytes) -> void* {
        void* p = ws + off;
        off += (bytes + 255) & ~(size_t)255;
        return p;
    };
    short*    dbf  = (short*)alloc((size_t)NVOC * DIM * 2);
    short*    xemb = (short*)alloc((size_t)SEQ * BAT * DIM * 2);
    short*    w0h  = (short*)alloc(2048ull * 512 * 2);
    short*    w0l  = (short*)alloc(2048ull * 512 * 2);
    float*    Gx   = (float*)alloc((size_t)SEQ * BAT * 2048 * 4);
    short*    hbuf = (short*)alloc(2ull * 129 * SLOT * 2);
    short*    adec = (short*)alloc((size_t)SEQ * BAT * HID * 2);
    unsigned* bar  = (unsigned*)alloc(256);

    prep_dec<<<(NVOC * DIM / 4 + 255) / 256, 256, 0, stream>>>(dw, dbf);
    prep_w0 <<<(2048 * 512 + 255) / 256, 256, 0, stream>>>(W0, w0h, w0l);
    embed_k <<<(SEQ * BAT * DIM / 4 + 255) / 256, 256, 0, stream>>>(toks, emb, xemb);
    {
        int ringU64 = 2 * 129 * SLOT / 4;
        init_k<<<(ringU64 + 255) / 256, 256, 0, stream>>>(hbuf, bar);
    }

    gx_gemm<<<32 * 16, 256, 0, stream>>>(xemb, w0h, w0l, Gx);

    rnn_k<<<NB + NDEC, 512, 0, stream>>>(W1, U0, U1, bias, Gx, hbuf, adec,
                                         dbf, db, out, bar);
}